// Round 4
// baseline (373.397 us; speedup 1.0000x reference)
//
#include <hip/hip_runtime.h>
#include <hip/hip_bf16.h>
#include <math.h>

#define B_ 8
#define W_ 1024
#define D_ 1024
#define R_ 64

typedef __hip_bfloat16 bf16;
typedef __attribute__((ext_vector_type(8))) short bf16x8;   // MFMA A/B frag (4 VGPRs)
typedef __attribute__((ext_vector_type(4))) float f32x4;    // MFMA C/D frag

__device__ __forceinline__ float tof(bf16 x) { return __bfloat162float(x); }
__device__ __forceinline__ short f2bs(float f) {
    bf16 b = __float2bfloat16(f);
    return *(short*)&b;
}

// async global->LDS, 16 bytes/lane; LDS dest = wave-uniform base + lane*16
__device__ __forceinline__ void async16(const void* g, void* l) {
    __builtin_amdgcn_global_load_lds(
        (const __attribute__((address_space(1))) unsigned int*)g,
        (__attribute__((address_space(3))) unsigned int*)l,
        16, 0, 0);
}

// ---------------------------------------------------------------------------
// RMSNorm: one block (256 threads) per row of D_=1024. fp32 in, bf16 out.
// ---------------------------------------------------------------------------
__global__ __launch_bounds__(256)
void rmsnorm_kernel(const float* __restrict__ src, const float* __restrict__ scale,
                    bf16* __restrict__ dst) {
    int row = blockIdx.x;
    const float* x = src + (size_t)row * D_;
    bf16* y = dst + (size_t)row * D_;
    float xv[4];
    float ss = 0.f;
#pragma unroll
    for (int it = 0; it < 4; ++it) {
        int d = threadIdx.x + it * 256;
        xv[it] = x[d];
        ss += xv[it] * xv[it];
    }
#pragma unroll
    for (int off = 32; off; off >>= 1) ss += __shfl_down(ss, off, 64);
    __shared__ float red[4];
    __shared__ float invs;
    int lane = threadIdx.x & 63, wid = threadIdx.x >> 6;
    if (lane == 0) red[wid] = ss;
    __syncthreads();
    if (threadIdx.x == 0) {
        float t = red[0] + red[1] + red[2] + red[3];
        invs = rsqrtf(t / (float)D_ + 1e-8f);
    }
    __syncthreads();
    float inv = invs;
#pragma unroll
    for (int it = 0; it < 4; ++it) {
        int d = threadIdx.x + it * 256;
        y[d] = __float2bfloat16(xv[it] * inv * scale[d]);
    }
}

// ---------------------------------------------------------------------------
// 64x64 LDS-tiled transpose: src[b][j][d] -> dst[b][d][j]  (bf16)
// ---------------------------------------------------------------------------
__global__ __launch_bounds__(256)
void transpose_kernel(const bf16* __restrict__ src, bf16* __restrict__ dst) {
    int b = blockIdx.z;
    int j0 = blockIdx.x * 64, d0 = blockIdx.y * 64;
    __shared__ short Ts[64][72];
    const bf16* S = src + (size_t)b * W_ * D_;
    bf16* Dd = dst + (size_t)b * W_ * D_;
    int tid = threadIdx.x;
    int r = tid >> 3, c = (tid & 7) * 8;
#pragma unroll
    for (int p = 0; p < 2; ++p) {
        int j = r + p * 32;
        bf16x8 vv = *(const bf16x8*)&S[(size_t)(j0 + j) * D_ + d0 + c];
#pragma unroll
        for (int e = 0; e < 8; ++e) Ts[j][c + e] = vv[e];
    }
    __syncthreads();
#pragma unroll
    for (int p = 0; p < 2; ++p) {
        int d = r + p * 32;
        bf16x8 vv;
#pragma unroll
        for (int e = 0; e < 8; ++e) vv[e] = Ts[c + e][d];
        *(bf16x8*)&Dd[(size_t)(d0 + d) * W_ + j0 + c] = vv;
    }
}

// ---------------------------------------------------------------------------
// uvT[r][d] (bf16, [128][1024]) from u[d][64] (z=0) and v[d][64] (z=1).
// ---------------------------------------------------------------------------
__global__ __launch_bounds__(256)
void uvT_kernel(const float* __restrict__ u, const float* __restrict__ v,
                bf16* __restrict__ uvT) {
    int g = blockIdx.z;
    int d0 = blockIdx.x * 64;
    const float* src = g ? v : u;
    __shared__ float Ts[64][65];
    int tid = threadIdx.x;
#pragma unroll
    for (int e = 0; e < 16; ++e) {
        int idx = tid + e * 256;
        int drow = idx >> 6, rcol = idx & 63;
        Ts[drow][rcol] = src[(size_t)(d0 + drow) * 64 + rcol];
    }
    __syncthreads();
#pragma unroll
    for (int e = 0; e < 16; ++e) {
        int idx = tid + e * 256;
        int orow = idx >> 6, ocol = idx & 63;
        uvT[(size_t)(g * 64 + orow) * D_ + d0 + ocol] = __float2bfloat16(Ts[ocol][orow]);
    }
}

// ---------------------------------------------------------------------------
// fp32 -> bf16 convert of the three weight matrices in ONE launch.
// ---------------------------------------------------------------------------
__global__ __launch_bounds__(256)
void convert3_kernel(const float* __restrict__ proj, const float* __restrict__ up,
                     const float* __restrict__ down,
                     bf16* __restrict__ projb, bf16* __restrict__ upb,
                     bf16* __restrict__ downb) {
    size_t idx = ((size_t)blockIdx.x * 256 + threadIdx.x) * 8;
    const size_t DD = (size_t)D_ * D_;
    const float* src; bf16* dst; size_t off;
    if (idx < DD)          { src = proj; dst = projb; off = idx; }
    else if (idx < 3 * DD) { src = up;   dst = upb;   off = idx - DD; }
    else                   { src = down; dst = downb; off = idx - 3 * DD; }
    float4 f0 = *(const float4*)(src + off);
    float4 f1 = *(const float4*)(src + off + 4);
    bf16x8 p;
    p[0] = f2bs(f0.x); p[1] = f2bs(f0.y); p[2] = f2bs(f0.z); p[3] = f2bs(f0.w);
    p[4] = f2bs(f1.x); p[5] = f2bs(f1.y); p[6] = f2bs(f1.z); p[7] = f2bs(f1.w);
    *(bf16x8*)(dst + off) = p;
}

// ---------------------------------------------------------------------------
// qk epilogue: sum SK=4 fp32 partials, l2norm halves, gamma^{+/-i} -> qg, kg.
// ---------------------------------------------------------------------------
__global__ __launch_bounds__(128)
void qk_epilogue_kernel(const float* __restrict__ qkraw,
                        const float* __restrict__ decay_logit,
                        float* __restrict__ qg, float* __restrict__ kg) {
    int row = blockIdx.x;          // b*W + i
    int i = row & (W_ - 1);
    int t = threadIdx.x;
    int r = t & 63;
    bool isK = t >= 64;
    const size_t PS = (size_t)B_ * W_ * 128;   // partial stride
    size_t off = (size_t)row * 128 + t;
    float val = qkraw[off] + qkraw[PS + off] + qkraw[2 * PS + off] + qkraw[3 * PS + off];
    float sq = val * val;
#pragma unroll
    for (int o = 32; o; o >>= 1) sq += __shfl_xor(sq, o, 64);
    val = val / fmaxf(sqrtf(sq), 1e-8f);

    float dl = decay_logit[r];
    float gamma = 0.15f + 0.85f * (1.f / (1.f + expf(-dl)));
    float lg = logf(gamma);
    float e = isK ? expf(-(float)i * lg) : expf((float)i * lg);
    float o = val * e;
    if (isK) kg[(size_t)row * R_ + r] = o;
    else     qg[(size_t)row * R_ + r] = o;
}

// ---------------------------------------------------------------------------
// M[b,i,j] = (j<=i) ? gate*k_base[i,j] + alpha * dot(qg[b,i,:], kg[b,j,:]) : 0
// ---------------------------------------------------------------------------
__global__ __launch_bounds__(256)
void buildM_kernel(const float* __restrict__ qg, const float* __restrict__ kg,
                   const float* __restrict__ k_base,
                   const float* __restrict__ gate_logit,
                   const float* __restrict__ alpha_logit,
                   bf16* __restrict__ M) {
    int b = blockIdx.z;
    int ti = blockIdx.y, tj = blockIdx.x;
    int i0 = ti * 32, j0 = tj * 32;
    int tx = threadIdx.x, ty = threadIdx.y;
    bf16* Mb = M + (size_t)b * W_ * W_;
    const bf16 zero = __float2bfloat16(0.f);

    if (tj > ti) {
#pragma unroll
        for (int a = 0; a < 2; ++a)
#pragma unroll
            for (int c = 0; c < 2; ++c)
                Mb[(size_t)(i0 + ty * 2 + a) * W_ + (j0 + tx * 2 + c)] = zero;
        return;
    }

    __shared__ float Qs[32][65];
    __shared__ float Ks[32][65];
    int tid = ty * 16 + tx;
    for (int e = tid; e < 32 * 64; e += 256) {
        int rr = e & 63, row = e >> 6;
        Qs[row][rr] = qg[((size_t)b * W_ + i0 + row) * R_ + rr];
        Ks[row][rr] = kg[((size_t)b * W_ + j0 + row) * R_ + rr];
    }
    __syncthreads();

    float acc[2][2] = {{0.f, 0.f}, {0.f, 0.f}};
#pragma unroll 8
    for (int r = 0; r < 64; ++r) {
        float qa = Qs[ty * 2 + 0][r], qb = Qs[ty * 2 + 1][r];
        float ka = Ks[tx * 2 + 0][r], kb = Ks[tx * 2 + 1][r];
        acc[0][0] += qa * ka; acc[0][1] += qa * kb;
        acc[1][0] += qb * ka; acc[1][1] += qb * kb;
    }

    float gate  = 1.f / (1.f + expf(-(*gate_logit)));
    float alpha = 1.f / (1.f + expf(-(*alpha_logit)));  // ALPHA_CAP = 1
#pragma unroll
    for (int a = 0; a < 2; ++a) {
#pragma unroll
        for (int c = 0; c < 2; ++c) {
            int i = i0 + ty * 2 + a, j = j0 + tx * 2 + c;
            float vkb = k_base[(size_t)i * W_ + j];
            float out = (j <= i) ? (gate * vkb + alpha * acc[a][c]) : 0.f;
            Mb[(size_t)i * W_ + j] = __float2bfloat16(out);
        }
    }
}

// ---------------------------------------------------------------------------
// shared GEMM helpers
// ---------------------------------------------------------------------------
#define BAR() do { __builtin_amdgcn_sched_barrier(0); \
                   __builtin_amdgcn_s_barrier(); \
                   __builtin_amdgcn_sched_barrier(0); } while (0)

__device__ __forceinline__ void mfma8(const bf16x8 (&fa)[2], const bf16x8 (&fb)[4],
                                      f32x4 (&acc)[2][4]) {
#pragma unroll
    for (int mi = 0; mi < 2; ++mi)
#pragma unroll
        for (int ni = 0; ni < 4; ++ni)
            acc[mi][ni] = __builtin_amdgcn_mfma_f32_16x16x32_bf16(
                fa[mi], fb[ni], acc[mi][ni], 0, 0, 0);
}

__device__ __forceinline__ void readf(const short* At0, const short* Bt0, int slot,
                                      const int (&ao)[2], const int (&bo)[4],
                                      bf16x8 (&fa)[2], bf16x8 (&fb)[4]) {
    const short* Ard = At0 + slot * 4096;
    const short* Brd = Bt0 + slot * 4096;
#pragma unroll
    for (int mi = 0; mi < 2; ++mi) fa[mi] = *(const bf16x8*)&Ard[ao[mi]];
#pragma unroll
    for (int ni = 0; ni < 4; ++ni) fb[ni] = *(const bf16x8*)&Brd[bo[ni]];
}

// ---------------------------------------------------------------------------
// OLD 128x128 MFMA GEMM (r15 5-slot ring) — kept ONLY for step 2 (N=128,
// split-K=4). Proven. EPI 5: Cout fp32 partial at z*sC.
// ---------------------------------------------------------------------------
template<int EPI, int SK>
__global__ __launch_bounds__(512, 4)
void mgemm_kernel(const bf16* __restrict__ A, const bf16* __restrict__ Bm,
                  const float* __restrict__ Res, const float* __restrict__ bias,
                  void* __restrict__ Cout,
                  int M, int N, int K,
                  long sA, long sB, long sC, int causal) {
    __shared__ __align__(16) short At[5][128 * 32];
    __shared__ __align__(16) short Bt[5][128 * 32];
    int z = blockIdx.z;
    const bf16* Ab = (SK > 1) ? A : A + (size_t)z * sA;
    const bf16* Bb = (SK > 1) ? Bm : Bm + (size_t)z * sB;
    int kchunk = K / SK;
    int kbeg = (SK > 1) ? z * kchunk : 0;
    int m0 = blockIdx.x * 128, n0 = blockIdx.y * 128;
    int tid = threadIdx.x;
    int lane = tid & 63, wave = tid >> 6;
    int wy = wave >> 1, wx = wave & 1;
    int quad = lane >> 4, l15 = lane & 15;

    f32x4 acc[2][4];
#pragma unroll
    for (int i = 0; i < 2; ++i)
#pragma unroll
        for (int j = 0; j < 4; ++j)
            acc[i][j] = (f32x4){0.f, 0.f, 0.f, 0.f};

    int kend = kbeg + kchunk;
    if (SK == 1 && causal) kend = (m0 + 128 < K) ? m0 + 128 : K;
    int nIter = (kend - kbeg) >> 5;

    int srcChunk = ((lane & 3) ^ ((lane >> 3) & 3)) * 8;
    size_t rowA = (size_t)(m0 + wave * 16 + (lane >> 2)) * K;
    size_t rowB = (size_t)(n0 + wave * 16 + (lane >> 2)) * K;
    const bf16* aP = Ab + rowA + srcChunk + kbeg;
    const bf16* bP = Bb + rowB + srcChunk + kbeg;
    short* aDst = &At[0][0] + wave * 512;
    short* bDst = &Bt[0][0] + wave * 512;

    int rswz = (quad ^ ((l15 >> 1) & 3)) * 8;
    int ao[2], bo[4];
#pragma unroll
    for (int mi = 0; mi < 2; ++mi) ao[mi] = (wy * 32 + mi * 16 + l15) * 32 + rswz;
#pragma unroll
    for (int ni = 0; ni < 4; ++ni) bo[ni] = (wx * 64 + ni * 16 + l15) * 32 + rswz;

#pragma unroll
    for (int p = 0; p < 4; ++p) {
        async16(aP, aDst + p * 4096);
        async16(bP, bDst + p * 4096);
        aP += 32; bP += 32;
    }
    asm volatile("s_waitcnt vmcnt(6)" ::: "memory");
    BAR();

    bf16x8 fa0[2], fb0[4], fa1[2], fb1[4];
    readf(&At[0][0], &Bt[0][0], 0, ao, bo, fa0, fb0);

    int sStage = 4;
    int sPf = 1;
    int nMain = nIter - 4;

    for (int t = 0; t < nMain; t += 2) {
        asm volatile("s_waitcnt vmcnt(4)" ::: "memory");
        BAR();
        async16(aP, aDst + sStage * 4096);
        async16(bP, bDst + sStage * 4096);
        aP += 32; bP += 32;
        sStage = (sStage == 4) ? 0 : sStage + 1;
        mfma8(fa0, fb0, acc);
        readf(&At[0][0], &Bt[0][0], sPf, ao, bo, fa1, fb1);
        sPf = (sPf == 4) ? 0 : sPf + 1;
        asm volatile("s_waitcnt vmcnt(4)" ::: "memory");
        BAR();
        async16(aP, aDst + sStage * 4096);
        async16(bP, bDst + sStage * 4096);
        aP += 32; bP += 32;
        sStage = (sStage == 4) ? 0 : sStage + 1;
        mfma8(fa1, fb1, acc);
        readf(&At[0][0], &Bt[0][0], sPf, ao, bo, fa0, fb0);
        sPf = (sPf == 4) ? 0 : sPf + 1;
    }

    asm volatile("s_waitcnt vmcnt(4)" ::: "memory");
    BAR();
    mfma8(fa0, fb0, acc);
    readf(&At[0][0], &Bt[0][0], sPf, ao, bo, fa1, fb1);
    sPf = (sPf == 4) ? 0 : sPf + 1;

    asm volatile("s_waitcnt vmcnt(2)" ::: "memory");
    BAR();
    mfma8(fa1, fb1, acc);
    readf(&At[0][0], &Bt[0][0], sPf, ao, bo, fa0, fb0);
    sPf = (sPf == 4) ? 0 : sPf + 1;

    asm volatile("s_waitcnt vmcnt(0)" ::: "memory");
    BAR();
    mfma8(fa0, fb0, acc);
    readf(&At[0][0], &Bt[0][0], sPf, ao, bo, fa1, fb1);

    mfma8(fa1, fb1, acc);

#pragma unroll
    for (int ni = 0; ni < 4; ++ni) {
        int col = n0 + wx * 64 + ni * 16 + l15;
        float bv = (EPI == 1 || EPI == 2) ? bias[col] : 0.f;
#pragma unroll
        for (int mi = 0; mi < 2; ++mi) {
            int row0 = m0 + wy * 32 + mi * 16 + quad * 4;
#pragma unroll
            for (int r = 0; r < 4; ++r) {
                size_t idx = (size_t)(row0 + r) * N + col;
                float val = acc[mi][ni][r];
                if constexpr (EPI == 0) {
                    ((bf16*)Cout)[(size_t)z * sC + idx] = __float2bfloat16(val);
                } else if constexpr (EPI == 1) {
                    ((float*)Cout)[idx] = val + bv + Res[idx];
                } else if constexpr (EPI == 2) {
                    val += bv;
                    val = 0.5f * val * (1.f + erff(val * 0.70710678118654752f));
                    ((bf16*)Cout)[idx] = __float2bfloat16(val);
                } else {
                    ((float*)Cout)[(size_t)z * sC + idx] = val;
                }
            }
        }
    }
}

// ---------------------------------------------------------------------------
// NEW 256x128 MFMA GEMM (round-16). C[m,n] = sum_k A[m,k]*B[n,k].
// *** Why: r15 counters + arithmetic show the DS-read pipe is SATURATED:
// 96 ds_read_b128/CU/iter-pair x ~12cyc = 1152 cyc ~= measured 1114 cyc.
// Frag-prefetch (latency fix) gained only 4% -> throughput-bound. Fix =
// fewer LDS-read bytes per FLOP: per-wave tile 32x64 -> 64x64 reads
// (64+64) rows per K-step for 16 MFMAs vs (32+64) for 8 (0.0625 vs 0.094
// B/MAC, -33%). Halved grid.x also halves B-panel HBM re-fetch.
// Geometry: BM=256 BN=128 BK=32, 512 thr = 8 waves as 4M x 2N, per-wave
// 64x64 out = acc f32x4[4][4]. Single frag set (no cross-iter prefetch:
// keeps unified regs <=128 so 2 blocks/CU = 16 waves can be resident;
// prefetch proved near-worthless in the throughput-bound regime).
// LDS: 3-slot ring x (A 16KB + B 8KB) = 72 KB/block (2 blocks = 144 KB).
// Pipeline depth 2 (counted vmcnt, loads/thread/tile = 3 = 2A+1B):
//   prologue: stage(0), stage(1); vmcnt(3); BAR
//   iter t: stage(t+2) | ds_read slot t%3 | 16 MFMA |
//           [t+1<n: vmcnt(t+2<n ? 3 : 0); BAR]
// Slot safety: stage(t+2) overwrites slot (t-1)%3 whose reads completed
// before the barrier we passed at the top of iter t. vmcnt is per-wave;
// each wave waits for ITS OWN tile-(t+1) loads before the barrier, so the
// barrier publishes the whole tile (established r14 invariant).
// Staging: wave w stages A rows [w*32,w*32+32) (2 async16: 16-row groups)
// and B rows [w*16,w*16+16) (1 async16). XOR chunk swizzle as proven:
// src chunk (lane&3)^((lane>>3)&3), read chunk quad^((l15>>1)&3) — the
// group-of-16-rows pattern is identical for both A groups and B.
// Grid XCD-TRANSPOSED: x = M-stripe (swizzle when %8==0), y = N-block,
// z = batch. EPI codes as old kernel (0/1/2).
// ---------------------------------------------------------------------------
__device__ __forceinline__ void mfma16(const bf16x8 (&fa)[4], const bf16x8 (&fb)[4],
                                       f32x4 (&acc)[4][4]) {
#pragma unroll
    for (int mi = 0; mi < 4; ++mi)
#pragma unroll
        for (int ni = 0; ni < 4; ++ni)
            acc[mi][ni] = __builtin_amdgcn_mfma_f32_16x16x32_bf16(
                fa[mi], fb[ni], acc[mi][ni], 0, 0, 0);
}

template<int EPI>
__global__ __launch_bounds__(512, 4)
void mgemm2_kernel(const bf16* __restrict__ A, const bf16* __restrict__ Bm,
                   const float* __restrict__ Res, const float* __restrict__ bias,
                   void* __restrict__ Cout,
                   int M, int N, int K, long sA, long sB, long sC, int causal) {
    __shared__ __align__(16) short At[3][256 * 32];   // 3 x 16 KB
    __shared__ __align__(16) short Bt[3][128 * 32];   // 3 x  8 KB
    int z = blockIdx.z;
    const bf16* Ab = A + (size_t)z * sA;
    const bf16* Bb = Bm + (size_t)z * sB;

    int bx = blockIdx.x, gx = gridDim.x;
    if ((gx & 7) == 0) { int cpx = gx >> 3; bx = (bx & 7) * cpx + (bx >> 3); }
    int m0 = bx * 256, n0 = blockIdx.y * 128;

    int tid = threadIdx.x;
    int lane = tid & 63, wave = tid >> 6;           // 8 waves
    int wm = wave >> 1, wn = wave & 1;              // 4M x 2N
    int quad = lane >> 4, l15 = lane & 15;

    f32x4 acc[4][4];
#pragma unroll
    for (int i = 0; i < 4; ++i)
#pragma unroll
        for (int j = 0; j < 4; ++j)
            acc[i][j] = (f32x4){0.f, 0.f, 0.f, 0.f};

    int kend = causal ? ((m0 + 256 < K) ? m0 + 256 : K) : K;
    int nIter = kend >> 5;                          // >= 8 at all call sites

    int srcChunk = ((lane & 3) ^ ((lane >> 3) & 3)) * 8;
    size_t rowA0 = (size_t)(m0 + wave * 32 + (lane >> 2)) * K;
    size_t rowB  = (size_t)(n0 + wave * 16 + (lane >> 2)) * K;
    const bf16* aP0 = Ab + rowA0 + srcChunk;
    const bf16* aP1 = aP0 + (size_t)16 * K;
    const bf16* bP  = Bb + rowB + srcChunk;
    short* aDst = &At[0][0] + wave * 1024;          // 32 rows x 32 shorts
    short* bDst = &Bt[0][0] + wave * 512;           // 16 rows x 32 shorts

    int rswz = (quad ^ ((l15 >> 1) & 3)) * 8;
    int ao[4], bo[4];
#pragma unroll
    for (int mi = 0; mi < 4; ++mi) ao[mi] = (wm * 64 + mi * 16 + l15) * 32 + rswz;
#pragma unroll
    for (int ni = 0; ni < 4; ++ni) bo[ni] = (wn * 64 + ni * 16 + l15) * 32 + rswz;

    // prologue: stage tiles 0,1 into slots 0,1; wait tile 0; publish
    async16(aP0, aDst);
    async16(aP1, aDst + 512);
    async16(bP,  bDst);
    aP0 += 32; aP1 += 32; bP += 32;
    if (nIter > 1) {
        async16(aP0, aDst + 8192);
        async16(aP1, aDst + 8192 + 512);
        async16(bP,  bDst + 4096);
        aP0 += 32; aP1 += 32; bP += 32;
        asm volatile("s_waitcnt vmcnt(3)" ::: "memory");
    } else {
        asm volatile("s_waitcnt vmcnt(0)" ::: "memory");
    }
    BAR();

    int sCur = 0;      // slot holding tile t
    int sStage = 2;    // slot for tile t+2

    for (int t = 0; t < nIter; ++t) {
        bool i2 = (t + 2 < nIter);
        if (i2) {
            async16(aP0, aDst + sStage * 8192);
            async16(aP1, aDst + sStage * 8192 + 512);
            async16(bP,  bDst + sStage * 4096);
            aP0 += 32; aP1 += 32; bP += 32;
            sStage = (sStage == 2) ? 0 : sStage + 1;
        }
        bf16x8 fa[4], fb[4];
        const short* Ard = &At[0][0] + sCur * 8192;
        const short* Brd = &Bt[0][0] + sCur * 4096;
#pragma unroll
        for (int mi = 0; mi < 4; ++mi) fa[mi] = *(const bf16x8*)&Ard[ao[mi]];
#pragma unroll
        for (int ni = 0; ni < 4; ++ni) fb[ni] = *(const bf16x8*)&Brd[bo[ni]];
        mfma16(fa, fb, acc);
        if (t + 1 < nIter) {
            if (i2) asm volatile("s_waitcnt vmcnt(3)" ::: "memory");
            else    asm volatile("s_waitcnt vmcnt(0)" ::: "memory");
            BAR();
            sCur = (sCur == 2) ? 0 : sCur + 1;
        }
    }

    // ---- epilogue ----
#pragma unroll
    for (int ni = 0; ni < 4; ++ni) {
        int col = n0 + wn * 64 + ni * 16 + l15;
        float bv = (EPI == 1 || EPI == 2) ? bias[col] : 0.f;
#pragma unroll
        for (int mi = 0; mi < 4; ++mi) {
            int row0 = m0 + wm * 64 + mi * 16 + quad * 4;
#pragma unroll
            for (int r = 0; r < 4; ++r) {
                size_t idx = (size_t)(row0 + r) * N + col;
                float val = acc[mi][ni][r];
                if constexpr (EPI == 0) {
                    ((bf16*)Cout)[(size_t)z * sC + idx] = __float2bfloat16(val);
                } else if constexpr (EPI == 1) {
                    ((float*)Cout)[idx] = val + bv + Res[idx];
                } else {
                    val += bv;
                    val = 0.5f * val * (1.f + erff(val * 0.70710678118654752f));
                    ((bf16*)Cout)[idx] = __float2bfloat16(val);
                }
            }
        }
    }
}

// ---------------------------------------------------------------------------
// Workspace (peak 62 MB):
//   [0,16)  : hnorm bf16 -> attn bf16 (step4 out) -> mnorm bf16 (step6 out)
//   [16,18) : uvT bf16 (dead after step 2) -> qg fp32 (written step 2b)
//   [18,20) : kg fp32
//   [20,36) : hnormT bf16            -+ tbuf bf16 [20,52) after step 4
//   [36,52) : qkraw fp32 4x4MB split-K partials (dead after 2b) -> Mbuf bf16
//   [52,54) : proj_w bf16   [54,58): up_w bf16   [58,62): down_w bf16
//   h1 lives in d_out (fp32); step 8 does same-index RMW (alias-safe).
// ---------------------------------------------------------------------------
extern "C" void kernel_launch(void* const* d_in, const int* in_sizes, int n_in,
                              void* d_out, int out_size, void* d_ws, size_t ws_size,
                              hipStream_t stream) {
    const float* h           = (const float*)d_in[0];
    const float* k_base      = (const float*)d_in[1];
    const float* decay_logit = (const float*)d_in[2];
    const float* gate_logit  = (const float*)d_in[3];
    const float* alpha_logit = (const float*)d_in[4];
    const float* u           = (const float*)d_in[5];
    const float* v           = (const float*)d_in[6];
    const float* proj_w      = (const float*)d_in[7];
    const float* proj_b      = (const float*)d_in[8];
    const float* norm1_scale = (const float*)d_in[9];
    const float* norm2_scale = (const float*)d_in[10];
    const float* up_w        = (const float*)d_in[11];
    const float* up_b        = (const float*)d_in[12];
    const float* down_w      = (const float*)d_in[13];
    const float* down_b      = (const float*)d_in[14];

    const size_t MB = 1048576;
    char* ws = (char*)d_ws;
    bf16*  hnorm   = (bf16*)(ws);                  // 16 MB
    bf16*  uvT     = (bf16*)(ws + 16 * MB);        // 256 KB (dead after step 2)
    float* qg      = (float*)(ws + 16 * MB);       //  2 MB (written step 2b)
    float* kg      = (float*)(ws + 18 * MB);       //  2 MB
    bf16*  hnormT  = (bf16*)(ws + 20 * MB);        // 16 MB
    float* qkraw   = (float*)(ws + 36 * MB);       // 16 MB partials (pre-buildM)
    bf16*  Mbuf    = (bf16*)(ws + 36 * MB);        // 16 MB (step 3 out)
    bf16*  proj_wb = (bf16*)(ws + 52 * MB);        //  2 MB
    bf16*  up_wb   = (bf16*)(ws + 54 * MB);        //  4 MB
    bf16*  down_wb = (bf16*)(ws + 58 * MB);        //  4 MB
    bf16*  attn    = hnorm;                        // [0,16) after qk GEMM
    bf16*  mnorm   = hnorm;
    bf16*  tbuf    = hnormT;                       // [20,52) after step 4
    float* h1      = (float*)d_out;

    // 0. weight conversions (single launch) + uvT
    convert3_kernel<<<5 * D_ * D_ / 2048, 256, 0, stream>>>(
        proj_w, up_w, down_w, proj_wb, up_wb, down_wb);
    uvT_kernel<<<dim3(D_ / 64, 1, 2), 256, 0, stream>>>(u, v, uvT);

    // 1. h_norm = rmsnorm(h, norm1_scale)
    rmsnorm_kernel<<<B_ * W_, 256, 0, stream>>>(h, norm1_scale, hnorm);

    // 1b. hnormT[b][d][j] = hnorm[b][j][d]
    transpose_kernel<<<dim3(W_ / 64, D_ / 64, B_), 256, 0, stream>>>(hnorm, hnormT);

    // 2. qkraw[z] = hnorm @ [u|v] K-chunk z (deterministic split-K=4)
    mgemm_kernel<5, 4><<<dim3(B_ * W_ / 128, 1, 4), 512, 0, stream>>>(
        hnorm, uvT, nullptr, nullptr, qkraw, B_ * W_, 128, D_,
        0, 0, (long)B_ * W_ * 128, 0);

    // 2b. sum partials, l2norm halves, gamma^{+/-i} -> qg, kg (fp32)
    qk_epilogue_kernel<<<B_ * W_, 128, 0, stream>>>(qkraw, decay_logit, qg, kg);

    // 3. M = causal * (gate*k_base + alpha*scores)
    buildM_kernel<<<dim3(W_ / 32, W_ / 32, B_), dim3(16, 16), 0, stream>>>(
        qg, kg, k_base, gate_logit, alpha_logit, Mbuf);

    // 4. attn = M @ hnorm  (B = hnormT, batched via z, causal k-trunc)
    mgemm2_kernel<0><<<dim3(W_ / 256, D_ / 128, B_), 512, 0, stream>>>(
        Mbuf, hnormT, nullptr, nullptr, attn, W_, D_, W_,
        (long)W_ * W_, (long)W_ * D_, (long)W_ * D_, 1);

    // 5. h1 = h + attn @ proj_w^T + proj_b   -> d_out (fp32)
    mgemm2_kernel<1><<<dim3(B_ * W_ / 256, D_ / 128, 1), 512, 0, stream>>>(
        attn, proj_wb, h, proj_b, h1, B_ * W_, D_, D_, 0, 0, 0, 0);

    // 6. mnorm = rmsnorm(h1, norm2_scale)
    rmsnorm_kernel<<<B_ * W_, 256, 0, stream>>>(h1, norm2_scale, mnorm);

    // 7. t = gelu(mnorm @ up_w^T + up_b)     -> tbuf (bf16)
    mgemm2_kernel<2><<<dim3(B_ * W_ / 256, 2 * D_ / 128, 1), 512, 0, stream>>>(
        mnorm, up_wb, nullptr, up_b, tbuf, B_ * W_, 2 * D_, D_, 0, 0, 0, 0);

    // 8. out = h1 + t @ down_w^T + down_b  (h1 aliases d_out, same-idx RMW)
    mgemm2_kernel<1><<<dim3(B_ * W_ / 256, D_ / 128, 1), 512, 0, stream>>>(
        tbuf, down_wb, h1, down_b, (float*)d_out, B_ * W_, D_, 2 * D_, 0, 0, 0, 0);
}

// Round 5
// 356.294 us; speedup vs baseline: 1.0480x; 1.0480x over previous
//
#include <hip/hip_runtime.h>
#include <hip/hip_bf16.h>
#include <math.h>

#define B_ 8
#define W_ 1024
#define D_ 1024
#define R_ 64

typedef __hip_bfloat16 bf16;
typedef __attribute__((ext_vector_type(8))) short bf16x8;   // MFMA A/B frag (4 VGPRs)
typedef __attribute__((ext_vector_type(4))) float f32x4;    // MFMA C/D frag

__device__ __forceinline__ float tof(bf16 x) { return __bfloat162float(x); }
__device__ __forceinline__ short f2bs(float f) {
    bf16 b = __float2bfloat16(f);
    return *(short*)&b;
}

// async global->LDS, 16 bytes/lane; LDS dest = wave-uniform base + lane*16
__device__ __forceinline__ void async16(const void* g, void* l) {
    __builtin_amdgcn_global_load_lds(
        (const __attribute__((address_space(1))) unsigned int*)g,
        (__attribute__((address_space(3))) unsigned int*)l,
        16, 0, 0);
}

// ---------------------------------------------------------------------------
// RMSNorm: one block (256 threads) per row of D_=1024. fp32 in, bf16 out.
// ---------------------------------------------------------------------------
__global__ __launch_bounds__(256)
void rmsnorm_kernel(const float* __restrict__ src, const float* __restrict__ scale,
                    bf16* __restrict__ dst) {
    int row = blockIdx.x;
    const float* x = src + (size_t)row * D_;
    bf16* y = dst + (size_t)row * D_;
    float xv[4];
    float ss = 0.f;
#pragma unroll
    for (int it = 0; it < 4; ++it) {
        int d = threadIdx.x + it * 256;
        xv[it] = x[d];
        ss += xv[it] * xv[it];
    }
#pragma unroll
    for (int off = 32; off; off >>= 1) ss += __shfl_down(ss, off, 64);
    __shared__ float red[4];
    __shared__ float invs;
    int lane = threadIdx.x & 63, wid = threadIdx.x >> 6;
    if (lane == 0) red[wid] = ss;
    __syncthreads();
    if (threadIdx.x == 0) {
        float t = red[0] + red[1] + red[2] + red[3];
        invs = rsqrtf(t / (float)D_ + 1e-8f);
    }
    __syncthreads();
    float inv = invs;
#pragma unroll
    for (int it = 0; it < 4; ++it) {
        int d = threadIdx.x + it * 256;
        y[d] = __float2bfloat16(xv[it] * inv * scale[d]);
    }
}

// ---------------------------------------------------------------------------
// 64x64 LDS-tiled transpose: src[b][j][d] -> dst[b][d][j]  (bf16)
// ---------------------------------------------------------------------------
__global__ __launch_bounds__(256)
void transpose_kernel(const bf16* __restrict__ src, bf16* __restrict__ dst) {
    int b = blockIdx.z;
    int j0 = blockIdx.x * 64, d0 = blockIdx.y * 64;
    __shared__ short Ts[64][72];
    const bf16* S = src + (size_t)b * W_ * D_;
    bf16* Dd = dst + (size_t)b * W_ * D_;
    int tid = threadIdx.x;
    int r = tid >> 3, c = (tid & 7) * 8;
#pragma unroll
    for (int p = 0; p < 2; ++p) {
        int j = r + p * 32;
        bf16x8 vv = *(const bf16x8*)&S[(size_t)(j0 + j) * D_ + d0 + c];
#pragma unroll
        for (int e = 0; e < 8; ++e) Ts[j][c + e] = vv[e];
    }
    __syncthreads();
#pragma unroll
    for (int p = 0; p < 2; ++p) {
        int d = r + p * 32;
        bf16x8 vv;
#pragma unroll
        for (int e = 0; e < 8; ++e) vv[e] = Ts[c + e][d];
        *(bf16x8*)&Dd[(size_t)(d0 + d) * W_ + j0 + c] = vv;
    }
}

// ---------------------------------------------------------------------------
// uvT[r][d] (bf16, [128][1024]) from u[d][64] (z=0) and v[d][64] (z=1).
// ---------------------------------------------------------------------------
__global__ __launch_bounds__(256)
void uvT_kernel(const float* __restrict__ u, const float* __restrict__ v,
                bf16* __restrict__ uvT) {
    int g = blockIdx.z;
    int d0 = blockIdx.x * 64;
    const float* src = g ? v : u;
    __shared__ float Ts[64][65];
    int tid = threadIdx.x;
#pragma unroll
    for (int e = 0; e < 16; ++e) {
        int idx = tid + e * 256;
        int drow = idx >> 6, rcol = idx & 63;
        Ts[drow][rcol] = src[(size_t)(d0 + drow) * 64 + rcol];
    }
    __syncthreads();
#pragma unroll
    for (int e = 0; e < 16; ++e) {
        int idx = tid + e * 256;
        int orow = idx >> 6, ocol = idx & 63;
        uvT[(size_t)(g * 64 + orow) * D_ + d0 + ocol] = __float2bfloat16(Ts[ocol][orow]);
    }
}

// ---------------------------------------------------------------------------
// fp32 -> bf16 convert of the three weight matrices in ONE launch.
// ---------------------------------------------------------------------------
__global__ __launch_bounds__(256)
void convert3_kernel(const float* __restrict__ proj, const float* __restrict__ up,
                     const float* __restrict__ down,
                     bf16* __restrict__ projb, bf16* __restrict__ upb,
                     bf16* __restrict__ downb) {
    size_t idx = ((size_t)blockIdx.x * 256 + threadIdx.x) * 8;
    const size_t DD = (size_t)D_ * D_;
    const float* src; bf16* dst; size_t off;
    if (idx < DD)          { src = proj; dst = projb; off = idx; }
    else if (idx < 3 * DD) { src = up;   dst = upb;   off = idx - DD; }
    else                   { src = down; dst = downb; off = idx - 3 * DD; }
    float4 f0 = *(const float4*)(src + off);
    float4 f1 = *(const float4*)(src + off + 4);
    bf16x8 p;
    p[0] = f2bs(f0.x); p[1] = f2bs(f0.y); p[2] = f2bs(f0.z); p[3] = f2bs(f0.w);
    p[4] = f2bs(f1.x); p[5] = f2bs(f1.y); p[6] = f2bs(f1.z); p[7] = f2bs(f1.w);
    *(bf16x8*)(dst + off) = p;
}

// ---------------------------------------------------------------------------
// qk epilogue: sum SK=4 fp32 partials, l2norm halves, gamma^{+/-i} -> qg, kg.
// ---------------------------------------------------------------------------
__global__ __launch_bounds__(128)
void qk_epilogue_kernel(const float* __restrict__ qkraw,
                        const float* __restrict__ decay_logit,
                        float* __restrict__ qg, float* __restrict__ kg) {
    int row = blockIdx.x;          // b*W + i
    int i = row & (W_ - 1);
    int t = threadIdx.x;
    int r = t & 63;
    bool isK = t >= 64;
    const size_t PS = (size_t)B_ * W_ * 128;   // partial stride
    size_t off = (size_t)row * 128 + t;
    float val = qkraw[off] + qkraw[PS + off] + qkraw[2 * PS + off] + qkraw[3 * PS + off];
    float sq = val * val;
#pragma unroll
    for (int o = 32; o; o >>= 1) sq += __shfl_xor(sq, o, 64);
    val = val / fmaxf(sqrtf(sq), 1e-8f);

    float dl = decay_logit[r];
    float gamma = 0.15f + 0.85f * (1.f / (1.f + expf(-dl)));
    float lg = logf(gamma);
    float e = isK ? expf(-(float)i * lg) : expf((float)i * lg);
    float o = val * e;
    if (isK) kg[(size_t)row * R_ + r] = o;
    else     qg[(size_t)row * R_ + r] = o;
}

// ---------------------------------------------------------------------------
// M[b,i,j] = (j<=i) ? gate*k_base[i,j] + alpha * dot(qg[b,i,:], kg[b,j,:]) : 0
// ---------------------------------------------------------------------------
__global__ __launch_bounds__(256)
void buildM_kernel(const float* __restrict__ qg, const float* __restrict__ kg,
                   const float* __restrict__ k_base,
                   const float* __restrict__ gate_logit,
                   const float* __restrict__ alpha_logit,
                   bf16* __restrict__ M) {
    int b = blockIdx.z;
    int ti = blockIdx.y, tj = blockIdx.x;
    int i0 = ti * 32, j0 = tj * 32;
    int tx = threadIdx.x, ty = threadIdx.y;
    bf16* Mb = M + (size_t)b * W_ * W_;
    const bf16 zero = __float2bfloat16(0.f);

    if (tj > ti) {
#pragma unroll
        for (int a = 0; a < 2; ++a)
#pragma unroll
            for (int c = 0; c < 2; ++c)
                Mb[(size_t)(i0 + ty * 2 + a) * W_ + (j0 + tx * 2 + c)] = zero;
        return;
    }

    __shared__ float Qs[32][65];
    __shared__ float Ks[32][65];
    int tid = ty * 16 + tx;
    for (int e = tid; e < 32 * 64; e += 256) {
        int rr = e & 63, row = e >> 6;
        Qs[row][rr] = qg[((size_t)b * W_ + i0 + row) * R_ + rr];
        Ks[row][rr] = kg[((size_t)b * W_ + j0 + row) * R_ + rr];
    }
    __syncthreads();

    float acc[2][2] = {{0.f, 0.f}, {0.f, 0.f}};
#pragma unroll 8
    for (int r = 0; r < 64; ++r) {
        float qa = Qs[ty * 2 + 0][r], qb = Qs[ty * 2 + 1][r];
        float ka = Ks[tx * 2 + 0][r], kb = Ks[tx * 2 + 1][r];
        acc[0][0] += qa * ka; acc[0][1] += qa * kb;
        acc[1][0] += qb * ka; acc[1][1] += qb * kb;
    }

    float gate  = 1.f / (1.f + expf(-(*gate_logit)));
    float alpha = 1.f / (1.f + expf(-(*alpha_logit)));  // ALPHA_CAP = 1
#pragma unroll
    for (int a = 0; a < 2; ++a) {
#pragma unroll
        for (int c = 0; c < 2; ++c) {
            int i = i0 + ty * 2 + a, j = j0 + tx * 2 + c;
            float vkb = k_base[(size_t)i * W_ + j];
            float out = (j <= i) ? (gate * vkb + alpha * acc[a][c]) : 0.f;
            Mb[(size_t)i * W_ + j] = __float2bfloat16(out);
        }
    }
}

// ---------------------------------------------------------------------------
// shared GEMM helpers
// ---------------------------------------------------------------------------
#define BAR() do { __builtin_amdgcn_sched_barrier(0); \
                   __builtin_amdgcn_s_barrier(); \
                   __builtin_amdgcn_sched_barrier(0); } while (0)

__device__ __forceinline__ void mfma8(const bf16x8 (&fa)[2], const bf16x8 (&fb)[4],
                                      f32x4 (&acc)[2][4]) {
#pragma unroll
    for (int mi = 0; mi < 2; ++mi)
#pragma unroll
        for (int ni = 0; ni < 4; ++ni)
            acc[mi][ni] = __builtin_amdgcn_mfma_f32_16x16x32_bf16(
                fa[mi], fb[ni], acc[mi][ni], 0, 0, 0);
}

__device__ __forceinline__ void readf(const short* At0, const short* Bt0, int slot,
                                      const int (&ao)[2], const int (&bo)[4],
                                      bf16x8 (&fa)[2], bf16x8 (&fb)[4]) {
    const short* Ard = At0 + slot * 4096;
    const short* Brd = Bt0 + slot * 4096;
#pragma unroll
    for (int mi = 0; mi < 2; ++mi) fa[mi] = *(const bf16x8*)&Ard[ao[mi]];
#pragma unroll
    for (int ni = 0; ni < 4; ++ni) fb[ni] = *(const bf16x8*)&Brd[bo[ni]];
}

__device__ __forceinline__ void mfma16(const bf16x8 (&fa)[4], const bf16x8 (&fb)[4],
                                       f32x4 (&acc)[4][4]) {
#pragma unroll
    for (int mi = 0; mi < 4; ++mi)
#pragma unroll
        for (int ni = 0; ni < 4; ++ni)
            acc[mi][ni] = __builtin_amdgcn_mfma_f32_16x16x32_bf16(
                fa[mi], fb[ni], acc[mi][ni], 0, 0, 0);
}

__device__ __forceinline__ void readf4(const short* At0, const short* Bt0, int slot,
                                       const int (&ao)[4], const int (&bo)[4],
                                       bf16x8 (&fa)[4], bf16x8 (&fb)[4]) {
    const short* Ard = At0 + slot * 4096;
    const short* Brd = Bt0 + slot * 4096;
#pragma unroll
    for (int mi = 0; mi < 4; ++mi) fa[mi] = *(const bf16x8*)&Ard[ao[mi]];
#pragma unroll
    for (int ni = 0; ni < 4; ++ni) fb[ni] = *(const bf16x8*)&Brd[bo[ni]];
}

// ---------------------------------------------------------------------------
// OLD 128x128 8-wave MFMA GEMM (r15 5-slot ring) — kept ONLY for step 2
// (N=128, split-K=4). Proven. EPI 5: Cout fp32 partial at z*sC.
// ---------------------------------------------------------------------------
template<int EPI, int SK>
__global__ __launch_bounds__(512, 4)
void mgemm_kernel(const bf16* __restrict__ A, const bf16* __restrict__ Bm,
                  const float* __restrict__ Res, const float* __restrict__ bias,
                  void* __restrict__ Cout,
                  int M, int N, int K,
                  long sA, long sB, long sC, int causal) {
    __shared__ __align__(16) short At[5][128 * 32];
    __shared__ __align__(16) short Bt[5][128 * 32];
    int z = blockIdx.z;
    const bf16* Ab = (SK > 1) ? A : A + (size_t)z * sA;
    const bf16* Bb = (SK > 1) ? Bm : Bm + (size_t)z * sB;
    int kchunk = K / SK;
    int kbeg = (SK > 1) ? z * kchunk : 0;
    int m0 = blockIdx.x * 128, n0 = blockIdx.y * 128;
    int tid = threadIdx.x;
    int lane = tid & 63, wave = tid >> 6;
    int wy = wave >> 1, wx = wave & 1;
    int quad = lane >> 4, l15 = lane & 15;

    f32x4 acc[2][4];
#pragma unroll
    for (int i = 0; i < 2; ++i)
#pragma unroll
        for (int j = 0; j < 4; ++j)
            acc[i][j] = (f32x4){0.f, 0.f, 0.f, 0.f};

    int kend = kbeg + kchunk;
    if (SK == 1 && causal) kend = (m0 + 128 < K) ? m0 + 128 : K;
    int nIter = (kend - kbeg) >> 5;

    int srcChunk = ((lane & 3) ^ ((lane >> 3) & 3)) * 8;
    size_t rowA = (size_t)(m0 + wave * 16 + (lane >> 2)) * K;
    size_t rowB = (size_t)(n0 + wave * 16 + (lane >> 2)) * K;
    const bf16* aP = Ab + rowA + srcChunk + kbeg;
    const bf16* bP = Bb + rowB + srcChunk + kbeg;
    short* aDst = &At[0][0] + wave * 512;
    short* bDst = &Bt[0][0] + wave * 512;

    int rswz = (quad ^ ((l15 >> 1) & 3)) * 8;
    int ao[2], bo[4];
#pragma unroll
    for (int mi = 0; mi < 2; ++mi) ao[mi] = (wy * 32 + mi * 16 + l15) * 32 + rswz;
#pragma unroll
    for (int ni = 0; ni < 4; ++ni) bo[ni] = (wx * 64 + ni * 16 + l15) * 32 + rswz;

#pragma unroll
    for (int p = 0; p < 4; ++p) {
        async16(aP, aDst + p * 4096);
        async16(bP, bDst + p * 4096);
        aP += 32; bP += 32;
    }
    asm volatile("s_waitcnt vmcnt(6)" ::: "memory");
    BAR();

    bf16x8 fa0[2], fb0[4], fa1[2], fb1[4];
    readf(&At[0][0], &Bt[0][0], 0, ao, bo, fa0, fb0);

    int sStage = 4;
    int sPf = 1;
    int nMain = nIter - 4;

    for (int t = 0; t < nMain; t += 2) {
        asm volatile("s_waitcnt vmcnt(4)" ::: "memory");
        BAR();
        async16(aP, aDst + sStage * 4096);
        async16(bP, bDst + sStage * 4096);
        aP += 32; bP += 32;
        sStage = (sStage == 4) ? 0 : sStage + 1;
        mfma8(fa0, fb0, acc);
        readf(&At[0][0], &Bt[0][0], sPf, ao, bo, fa1, fb1);
        sPf = (sPf == 4) ? 0 : sPf + 1;
        asm volatile("s_waitcnt vmcnt(4)" ::: "memory");
        BAR();
        async16(aP, aDst + sStage * 4096);
        async16(bP, bDst + sStage * 4096);
        aP += 32; bP += 32;
        sStage = (sStage == 4) ? 0 : sStage + 1;
        mfma8(fa1, fb1, acc);
        readf(&At[0][0], &Bt[0][0], sPf, ao, bo, fa0, fb0);
        sPf = (sPf == 4) ? 0 : sPf + 1;
    }

    asm volatile("s_waitcnt vmcnt(4)" ::: "memory");
    BAR();
    mfma8(fa0, fb0, acc);
    readf(&At[0][0], &Bt[0][0], sPf, ao, bo, fa1, fb1);
    sPf = (sPf == 4) ? 0 : sPf + 1;

    asm volatile("s_waitcnt vmcnt(2)" ::: "memory");
    BAR();
    mfma8(fa1, fb1, acc);
    readf(&At[0][0], &Bt[0][0], sPf, ao, bo, fa0, fb0);
    sPf = (sPf == 4) ? 0 : sPf + 1;

    asm volatile("s_waitcnt vmcnt(0)" ::: "memory");
    BAR();
    mfma8(fa0, fb0, acc);
    readf(&At[0][0], &Bt[0][0], sPf, ao, bo, fa1, fb1);

    mfma8(fa1, fb1, acc);

#pragma unroll
    for (int ni = 0; ni < 4; ++ni) {
        int col = n0 + wx * 64 + ni * 16 + l15;
        float bv = (EPI == 1 || EPI == 2) ? bias[col] : 0.f;
#pragma unroll
        for (int mi = 0; mi < 2; ++mi) {
            int row0 = m0 + wy * 32 + mi * 16 + quad * 4;
#pragma unroll
            for (int r = 0; r < 4; ++r) {
                size_t idx = (size_t)(row0 + r) * N + col;
                float val = acc[mi][ni][r];
                if constexpr (EPI == 0) {
                    ((bf16*)Cout)[(size_t)z * sC + idx] = __float2bfloat16(val);
                } else if constexpr (EPI == 1) {
                    ((float*)Cout)[idx] = val + bv + Res[idx];
                } else if constexpr (EPI == 2) {
                    val += bv;
                    val = 0.5f * val * (1.f + erff(val * 0.70710678118654752f));
                    ((bf16*)Cout)[idx] = __float2bfloat16(val);
                } else {
                    ((float*)Cout)[(size_t)z * sC + idx] = val;
                }
            }
        }
    }
}

// ---------------------------------------------------------------------------
// NEW 128x128 4-WAVE MFMA GEMM (round-17). C[m,n] = sum_k A[m,k]*B[n,k].
// *** Synthesis of r15/r16 evidence:
//  - r15 (128^2, 8 waves, 32x64/wave): DS pipe SATURATED (48 b128/block-iter
//    x 2 blk x ~12cyc ~= measured 1114 cyc/2-block-iters).
//  - r16 (256x128, 8 waves, 64x64/wave): DS/FLOP -33% but grid 256 -> 1
//    barrier-locked block/CU, occupancy 36->19, REGRESSED to 66us.
// This kernel keeps 64x64/wave (0.0625 B/MAC) in a 128x128 tile with FOUR
// waves (256 thr, 2Mx2N), so grids stay 512-1024 blocks -> 2 independent
// blocks/CU (un-synchronized: their drains/compute overlap, m114), and keeps
// the PROVEN depth-3 counted-vmcnt + frag-prefetch pipeline:
// 4-slot ring x (A 8KB + B 8KB) = 64 KB/block, 2 blocks = 128 KB.
// Per-CU DS load: 2 x 32 b128/block-iter ~= 640 cyc/2-block-iters (was 1114).
// Pipeline: prologue stage 0,1,2 (12 loads), vmcnt(8) [tile0 landed], BAR,
// prefetch frags(0). Iter t: vmcnt(4 if t+2<n else 0) [tile t+1 landed],
// BAR [publish], stage(t+3) if exists, mfma(frags t), prefetch frags(t+1).
// Tail = last 2 iters (nIter even, >=4 at all call sites).
// Slot safety: stage(t+3)->slot (t-1)&3; tile t-1's frags were prefetched
// at iter t-2, a barrier before the stage issues. vmcnt is per-wave; all
// waves wait their own loads then barrier -> tile published (r14 invariant).
// Staging: wave w stages A rows [w*32,w*32+32) and B rows [w*32,w*32+32),
// 2 async16 each (16-row groups), XOR chunk swizzle as proven (2-way max
// read conflict = free; measured 0 all rounds).
// Grid XCD-TRANSPOSED: x = M-stripe (swizzle when %8==0), y = N, z = batch.
// EPI 0/1/2 as before. REQUIRES K mult of 128 (nIter even >= 4).
// ---------------------------------------------------------------------------
template<int EPI>
__global__ __launch_bounds__(256, 2)
void mgemm3_kernel(const bf16* __restrict__ A, const bf16* __restrict__ Bm,
                   const float* __restrict__ Res, const float* __restrict__ bias,
                   void* __restrict__ Cout,
                   int M, int N, int K, long sA, long sB, long sC, int causal) {
    __shared__ __align__(16) short At[4][128 * 32];   // 4 x 8 KB
    __shared__ __align__(16) short Bt[4][128 * 32];   // 4 x 8 KB
    int z = blockIdx.z;
    const bf16* Ab = A + (size_t)z * sA;
    const bf16* Bb = Bm + (size_t)z * sB;

    int bx = blockIdx.x, gx = gridDim.x;
    if ((gx & 7) == 0) { int cpx = gx >> 3; bx = (bx & 7) * cpx + (bx >> 3); }
    int m0 = bx * 128, n0 = blockIdx.y * 128;

    int tid = threadIdx.x;
    int lane = tid & 63, wave = tid >> 6;           // 4 waves
    int wm = wave >> 1, wn = wave & 1;              // 2M x 2N, 64x64 each
    int quad = lane >> 4, l15 = lane & 15;

    f32x4 acc[4][4];
#pragma unroll
    for (int i = 0; i < 4; ++i)
#pragma unroll
        for (int j = 0; j < 4; ++j)
            acc[i][j] = (f32x4){0.f, 0.f, 0.f, 0.f};

    int kend = causal ? ((m0 + 128 < K) ? m0 + 128 : K) : K;
    int nIter = kend >> 5;                          // even, >= 4

    int srcChunk = ((lane & 3) ^ ((lane >> 3) & 3)) * 8;
    const bf16* aP0 = Ab + (size_t)(m0 + wave * 32 + (lane >> 2)) * K + srcChunk;
    const bf16* aP1 = aP0 + (size_t)16 * K;
    const bf16* bP0 = Bb + (size_t)(n0 + wave * 32 + (lane >> 2)) * K + srcChunk;
    const bf16* bP1 = bP0 + (size_t)16 * K;
    short* aDst = &At[0][0] + wave * 1024;          // 32 rows x 32 shorts
    short* bDst = &Bt[0][0] + wave * 1024;

    int rswz = (quad ^ ((l15 >> 1) & 3)) * 8;
    int ao[4], bo[4];
#pragma unroll
    for (int mi = 0; mi < 4; ++mi) ao[mi] = (wm * 64 + mi * 16 + l15) * 32 + rswz;
#pragma unroll
    for (int ni = 0; ni < 4; ++ni) bo[ni] = (wn * 64 + ni * 16 + l15) * 32 + rswz;

#define STG3(slot) do { \
        short* _a = aDst + (slot) * 4096; \
        short* _b = bDst + (slot) * 4096; \
        async16(aP0, _a); async16(aP1, _a + 512); \
        async16(bP0, _b); async16(bP1, _b + 512); \
        aP0 += 32; aP1 += 32; bP0 += 32; bP1 += 32; \
    } while (0)

    // prologue: stage tiles 0,1,2 (12 loads); tile 0 landed; prefetch frags 0
    STG3(0); STG3(1); STG3(2);
    asm volatile("s_waitcnt vmcnt(8)" ::: "memory");
    BAR();

    bf16x8 fa0[4], fb0[4], fa1[4], fb1[4];
    readf4(&At[0][0], &Bt[0][0], 0, ao, bo, fa0, fb0);

    int sStage = 3;   // slot for next staged tile
    int sPf = 1;      // slot for next prefetched tile
    int nMain = nIter - 2;   // even >= 2

    for (int t = 0; t < nMain; t += 2) {
        // ---- iter t (set0): tile t+2 exists (t < nMain) -> vmcnt(4) ----
        asm volatile("s_waitcnt vmcnt(4)" ::: "memory");
        BAR();
        if (t + 3 < nIter) { STG3(sStage & 3); ++sStage; }
        mfma16(fa0, fb0, acc);
        readf4(&At[0][0], &Bt[0][0], sPf & 3, ao, bo, fa1, fb1);
        ++sPf;
        // ---- iter t+1 (set1) ----
        if (t + 3 < nIter) asm volatile("s_waitcnt vmcnt(4)" ::: "memory");
        else               asm volatile("s_waitcnt vmcnt(0)" ::: "memory");
        BAR();
        if (t + 4 < nIter) { STG3(sStage & 3); ++sStage; }
        mfma16(fa1, fb1, acc);
        readf4(&At[0][0], &Bt[0][0], sPf & 3, ao, bo, fa0, fb0);
        ++sPf;
    }

    // ---- tail: iters nIter-2 (set0), nIter-1 (set1) ----
    asm volatile("s_waitcnt vmcnt(0)" ::: "memory");
    BAR();
    mfma16(fa0, fb0, acc);
    readf4(&At[0][0], &Bt[0][0], sPf & 3, ao, bo, fa1, fb1);
    mfma16(fa1, fb1, acc);
#undef STG3

    // ---- epilogue ----
#pragma unroll
    for (int ni = 0; ni < 4; ++ni) {
        int col = n0 + wn * 64 + ni * 16 + l15;
        float bv = (EPI == 1 || EPI == 2) ? bias[col] : 0.f;
#pragma unroll
        for (int mi = 0; mi < 4; ++mi) {
            int row0 = m0 + wm * 64 + mi * 16 + quad * 4;
#pragma unroll
            for (int r = 0; r < 4; ++r) {
                size_t idx = (size_t)(row0 + r) * N + col;
                float val = acc[mi][ni][r];
                if constexpr (EPI == 0) {
                    ((bf16*)Cout)[(size_t)z * sC + idx] = __float2bfloat16(val);
                } else if constexpr (EPI == 1) {
                    ((float*)Cout)[idx] = val + bv + Res[idx];
                } else {
                    val += bv;
                    val = 0.5f * val * (1.f + erff(val * 0.70710678118654752f));
                    ((bf16*)Cout)[idx] = __float2bfloat16(val);
                }
            }
        }
    }
}

// ---------------------------------------------------------------------------
// Workspace (peak 62 MB):
//   [0,16)  : hnorm bf16 -> attn bf16 (step4 out) -> mnorm bf16 (step6 out)
//   [16,18) : uvT bf16 (dead after step 2) -> qg fp32 (written step 2b)
//   [18,20) : kg fp32
//   [20,36) : hnormT bf16            -+ tbuf bf16 [20,52) after step 4
//   [36,52) : qkraw fp32 4x4MB split-K partials (dead after 2b) -> Mbuf bf16
//   [52,54) : proj_w bf16   [54,58): up_w bf16   [58,62): down_w bf16
//   h1 lives in d_out (fp32); step 8 does same-index RMW (alias-safe).
// ---------------------------------------------------------------------------
extern "C" void kernel_launch(void* const* d_in, const int* in_sizes, int n_in,
                              void* d_out, int out_size, void* d_ws, size_t ws_size,
                              hipStream_t stream) {
    const float* h           = (const float*)d_in[0];
    const float* k_base      = (const float*)d_in[1];
    const float* decay_logit = (const float*)d_in[2];
    const float* gate_logit  = (const float*)d_in[3];
    const float* alpha_logit = (const float*)d_in[4];
    const float* u           = (const float*)d_in[5];
    const float* v           = (const float*)d_in[6];
    const float* proj_w      = (const float*)d_in[7];
    const float* proj_b      = (const float*)d_in[8];
    const float* norm1_scale = (const float*)d_in[9];
    const float* norm2_scale = (const float*)d_in[10];
    const float* up_w        = (const float*)d_in[11];
    const float* up_b        = (const float*)d_in[12];
    const float* down_w      = (const float*)d_in[13];
    const float* down_b      = (const float*)d_in[14];

    const size_t MB = 1048576;
    char* ws = (char*)d_ws;
    bf16*  hnorm   = (bf16*)(ws);                  // 16 MB
    bf16*  uvT     = (bf16*)(ws + 16 * MB);        // 256 KB (dead after step 2)
    float* qg      = (float*)(ws + 16 * MB);       //  2 MB (written step 2b)
    float* kg      = (float*)(ws + 18 * MB);       //  2 MB
    bf16*  hnormT  = (bf16*)(ws + 20 * MB);        // 16 MB
    float* qkraw   = (float*)(ws + 36 * MB);       // 16 MB partials (pre-buildM)
    bf16*  Mbuf    = (bf16*)(ws + 36 * MB);        // 16 MB (step 3 out)
    bf16*  proj_wb = (bf16*)(ws + 52 * MB);        //  2 MB
    bf16*  up_wb   = (bf16*)(ws + 54 * MB);        //  4 MB
    bf16*  down_wb = (bf16*)(ws + 58 * MB);        //  4 MB
    bf16*  attn    = hnorm;                        // [0,16) after qk GEMM
    bf16*  mnorm   = hnorm;
    bf16*  tbuf    = hnormT;                       // [20,52) after step 4
    float* h1      = (float*)d_out;

    // 0. weight conversions (single launch) + uvT
    convert3_kernel<<<5 * D_ * D_ / 2048, 256, 0, stream>>>(
        proj_w, up_w, down_w, proj_wb, up_wb, down_wb);
    uvT_kernel<<<dim3(D_ / 64, 1, 2), 256, 0, stream>>>(u, v, uvT);

    // 1. h_norm = rmsnorm(h, norm1_scale)
    rmsnorm_kernel<<<B_ * W_, 256, 0, stream>>>(h, norm1_scale, hnorm);

    // 1b. hnormT[b][d][j] = hnorm[b][j][d]
    transpose_kernel<<<dim3(W_ / 64, D_ / 64, B_), 256, 0, stream>>>(hnorm, hnormT);

    // 2. qkraw[z] = hnorm @ [u|v] K-chunk z (deterministic split-K=4)
    mgemm_kernel<5, 4><<<dim3(B_ * W_ / 128, 1, 4), 512, 0, stream>>>(
        hnorm, uvT, nullptr, nullptr, qkraw, B_ * W_, 128, D_,
        0, 0, (long)B_ * W_ * 128, 0);

    // 2b. sum partials, l2norm halves, gamma^{+/-i} -> qg, kg (fp32)
    qk_epilogue_kernel<<<B_ * W_, 128, 0, stream>>>(qkraw, decay_logit, qg, kg);

    // 3. M = causal * (gate*k_base + alpha*scores)
    buildM_kernel<<<dim3(W_ / 32, W_ / 32, B_), dim3(16, 16), 0, stream>>>(
        qg, kg, k_base, gate_logit, alpha_logit, Mbuf);

    // 4. attn = M @ hnorm  (B = hnormT, batched via z, causal k-trunc)
    mgemm3_kernel<0><<<dim3(W_ / 128, D_ / 128, B_), 256, 0, stream>>>(
        Mbuf, hnormT, nullptr, nullptr, attn, W_, D_, W_,
        (long)W_ * W_, (long)W_ * D_, (long)W_ * D_, 1);

    // 5. h1 = h + attn @ proj_w^T + proj_b   -> d_out (fp32)
    mgemm3_kernel<1><<<dim3(B_ * W_ / 128, D_ / 128, 1), 256, 0, stream>>>(
        attn, proj_wb, h, proj_b, h1, B_ * W_, D_, D_, 0, 0, 0, 0);

    // 6. mnorm = rmsnorm(h1, norm2_scale)
    rmsnorm_kernel<<<B_ * W_, 256, 0, stream>>>(h1, norm2_scale, mnorm);

    // 7. t = gelu(mnorm @ up_w^T + up_b)     -> tbuf (bf16)
    mgemm3_kernel<2><<<dim3(B_ * W_ / 128, 2 * D_ / 128, 1), 256, 0, stream>>>(
        mnorm, up_wb, nullptr, up_b, tbuf, B_ * W_, 2 * D_, D_, 0, 0, 0, 0);

    // 8. out = h1 + t @ down_w^T + down_b  (h1 aliases d_out, same-idx RMW)
    mgemm3_kernel<1><<<dim3(B_ * W_ / 128, D_ / 128, 1), 256, 0, stream>>>(
        tbuf, down_wb, h1, down_b, (float*)d_out, B_ * W_, D_, 2 * D_, 0, 0, 0, 0);
}

// Round 6
// 351.085 us; speedup vs baseline: 1.0636x; 1.0148x over previous
//
#include <hip/hip_runtime.h>
#include <hip/hip_bf16.h>
#include <math.h>

#define B_ 8
#define W_ 1024
#define D_ 1024
#define R_ 64

typedef __hip_bfloat16 bf16;
typedef __attribute__((ext_vector_type(8))) short bf16x8;   // MFMA A/B frag (4 VGPRs)
typedef __attribute__((ext_vector_type(4))) float f32x4;    // MFMA C/D frag

__device__ __forceinline__ float tof(bf16 x) { return __bfloat162float(x); }
__device__ __forceinline__ short f2bs(float f) {
    bf16 b = __float2bfloat16(f);
    return *(short*)&b;
}

// async global->LDS, 16 bytes/lane; LDS dest = wave-uniform base + lane*16
__device__ __forceinline__ void async16(const void* g, void* l) {
    __builtin_amdgcn_global_load_lds(
        (const __attribute__((address_space(1))) unsigned int*)g,
        (__attribute__((address_space(3))) unsigned int*)l,
        16, 0, 0);
}

// ---------------------------------------------------------------------------
// RMSNorm: one block (256 threads) per row of D_=1024. fp32 in, bf16 out.
// ---------------------------------------------------------------------------
__global__ __launch_bounds__(256)
void rmsnorm_kernel(const float* __restrict__ src, const float* __restrict__ scale,
                    bf16* __restrict__ dst) {
    int row = blockIdx.x;
    const float* x = src + (size_t)row * D_;
    bf16* y = dst + (size_t)row * D_;
    float xv[4];
    float ss = 0.f;
#pragma unroll
    for (int it = 0; it < 4; ++it) {
        int d = threadIdx.x + it * 256;
        xv[it] = x[d];
        ss += xv[it] * xv[it];
    }
#pragma unroll
    for (int off = 32; off; off >>= 1) ss += __shfl_down(ss, off, 64);
    __shared__ float red[4];
    __shared__ float invs;
    int lane = threadIdx.x & 63, wid = threadIdx.x >> 6;
    if (lane == 0) red[wid] = ss;
    __syncthreads();
    if (threadIdx.x == 0) {
        float t = red[0] + red[1] + red[2] + red[3];
        invs = rsqrtf(t / (float)D_ + 1e-8f);
    }
    __syncthreads();
    float inv = invs;
#pragma unroll
    for (int it = 0; it < 4; ++it) {
        int d = threadIdx.x + it * 256;
        y[d] = __float2bfloat16(xv[it] * inv * scale[d]);
    }
}

// ---------------------------------------------------------------------------
// 64x64 LDS-tiled transpose: src[b][j][d] -> dst[b][d][j]  (bf16)
// ---------------------------------------------------------------------------
__global__ __launch_bounds__(256)
void transpose_kernel(const bf16* __restrict__ src, bf16* __restrict__ dst) {
    int b = blockIdx.z;
    int j0 = blockIdx.x * 64, d0 = blockIdx.y * 64;
    __shared__ short Ts[64][72];
    const bf16* S = src + (size_t)b * W_ * D_;
    bf16* Dd = dst + (size_t)b * W_ * D_;
    int tid = threadIdx.x;
    int r = tid >> 3, c = (tid & 7) * 8;
#pragma unroll
    for (int p = 0; p < 2; ++p) {
        int j = r + p * 32;
        bf16x8 vv = *(const bf16x8*)&S[(size_t)(j0 + j) * D_ + d0 + c];
#pragma unroll
        for (int e = 0; e < 8; ++e) Ts[j][c + e] = vv[e];
    }
    __syncthreads();
#pragma unroll
    for (int p = 0; p < 2; ++p) {
        int d = r + p * 32;
        bf16x8 vv;
#pragma unroll
        for (int e = 0; e < 8; ++e) vv[e] = Ts[c + e][d];
        *(bf16x8*)&Dd[(size_t)(d0 + d) * W_ + j0 + c] = vv;
    }
}

// ---------------------------------------------------------------------------
// uvT[r][d] (bf16, [128][1024]) from u[d][64] (z=0) and v[d][64] (z=1).
// ---------------------------------------------------------------------------
__global__ __launch_bounds__(256)
void uvT_kernel(const float* __restrict__ u, const float* __restrict__ v,
                bf16* __restrict__ uvT) {
    int g = blockIdx.z;
    int d0 = blockIdx.x * 64;
    const float* src = g ? v : u;
    __shared__ float Ts[64][65];
    int tid = threadIdx.x;
#pragma unroll
    for (int e = 0; e < 16; ++e) {
        int idx = tid + e * 256;
        int drow = idx >> 6, rcol = idx & 63;
        Ts[drow][rcol] = src[(size_t)(d0 + drow) * 64 + rcol];
    }
    __syncthreads();
#pragma unroll
    for (int e = 0; e < 16; ++e) {
        int idx = tid + e * 256;
        int orow = idx >> 6, ocol = idx & 63;
        uvT[(size_t)(g * 64 + orow) * D_ + d0 + ocol] = __float2bfloat16(Ts[ocol][orow]);
    }
}

// ---------------------------------------------------------------------------
// fp32 -> bf16 convert of the three weight matrices in ONE launch.
// ---------------------------------------------------------------------------
__global__ __launch_bounds__(256)
void convert3_kernel(const float* __restrict__ proj, const float* __restrict__ up,
                     const float* __restrict__ down,
                     bf16* __restrict__ projb, bf16* __restrict__ upb,
                     bf16* __restrict__ downb) {
    size_t idx = ((size_t)blockIdx.x * 256 + threadIdx.x) * 8;
    const size_t DD = (size_t)D_ * D_;
    const float* src; bf16* dst; size_t off;
    if (idx < DD)          { src = proj; dst = projb; off = idx; }
    else if (idx < 3 * DD) { src = up;   dst = upb;   off = idx - DD; }
    else                   { src = down; dst = downb; off = idx - 3 * DD; }
    float4 f0 = *(const float4*)(src + off);
    float4 f1 = *(const float4*)(src + off + 4);
    bf16x8 p;
    p[0] = f2bs(f0.x); p[1] = f2bs(f0.y); p[2] = f2bs(f0.z); p[3] = f2bs(f0.w);
    p[4] = f2bs(f1.x); p[5] = f2bs(f1.y); p[6] = f2bs(f1.z); p[7] = f2bs(f1.w);
    *(bf16x8*)(dst + off) = p;
}

// ---------------------------------------------------------------------------
// qk epilogue: sum SK=4 fp32 partials, l2norm halves, gamma^{+/-i} -> qg, kg.
// ---------------------------------------------------------------------------
__global__ __launch_bounds__(128)
void qk_epilogue_kernel(const float* __restrict__ qkraw,
                        const float* __restrict__ decay_logit,
                        float* __restrict__ qg, float* __restrict__ kg) {
    int row = blockIdx.x;          // b*W + i
    int i = row & (W_ - 1);
    int t = threadIdx.x;
    int r = t & 63;
    bool isK = t >= 64;
    const size_t PS = (size_t)B_ * W_ * 128;   // partial stride
    size_t off = (size_t)row * 128 + t;
    float val = qkraw[off] + qkraw[PS + off] + qkraw[2 * PS + off] + qkraw[3 * PS + off];
    float sq = val * val;
#pragma unroll
    for (int o = 32; o; o >>= 1) sq += __shfl_xor(sq, o, 64);
    val = val / fmaxf(sqrtf(sq), 1e-8f);

    float dl = decay_logit[r];
    float gamma = 0.15f + 0.85f * (1.f / (1.f + expf(-dl)));
    float lg = logf(gamma);
    float e = isK ? expf(-(float)i * lg) : expf((float)i * lg);
    float o = val * e;
    if (isK) kg[(size_t)row * R_ + r] = o;
    else     qg[(size_t)row * R_ + r] = o;
}

// ---------------------------------------------------------------------------
// M[b,i,j] = (j<=i) ? gate*k_base[i,j] + alpha * dot(qg[b,i,:], kg[b,j,:]) : 0
// ---------------------------------------------------------------------------
__global__ __launch_bounds__(256)
void buildM_kernel(const float* __restrict__ qg, const float* __restrict__ kg,
                   const float* __restrict__ k_base,
                   const float* __restrict__ gate_logit,
                   const float* __restrict__ alpha_logit,
                   bf16* __restrict__ M) {
    int b = blockIdx.z;
    int ti = blockIdx.y, tj = blockIdx.x;
    int i0 = ti * 32, j0 = tj * 32;
    int tx = threadIdx.x, ty = threadIdx.y;
    bf16* Mb = M + (size_t)b * W_ * W_;
    const bf16 zero = __float2bfloat16(0.f);

    if (tj > ti) {
#pragma unroll
        for (int a = 0; a < 2; ++a)
#pragma unroll
            for (int c = 0; c < 2; ++c)
                Mb[(size_t)(i0 + ty * 2 + a) * W_ + (j0 + tx * 2 + c)] = zero;
        return;
    }

    __shared__ float Qs[32][65];
    __shared__ float Ks[32][65];
    int tid = ty * 16 + tx;
    for (int e = tid; e < 32 * 64; e += 256) {
        int rr = e & 63, row = e >> 6;
        Qs[row][rr] = qg[((size_t)b * W_ + i0 + row) * R_ + rr];
        Ks[row][rr] = kg[((size_t)b * W_ + j0 + row) * R_ + rr];
    }
    __syncthreads();

    float acc[2][2] = {{0.f, 0.f}, {0.f, 0.f}};
#pragma unroll 8
    for (int r = 0; r < 64; ++r) {
        float qa = Qs[ty * 2 + 0][r], qb = Qs[ty * 2 + 1][r];
        float ka = Ks[tx * 2 + 0][r], kb = Ks[tx * 2 + 1][r];
        acc[0][0] += qa * ka; acc[0][1] += qa * kb;
        acc[1][0] += qb * ka; acc[1][1] += qb * kb;
    }

    float gate  = 1.f / (1.f + expf(-(*gate_logit)));
    float alpha = 1.f / (1.f + expf(-(*alpha_logit)));  // ALPHA_CAP = 1
#pragma unroll
    for (int a = 0; a < 2; ++a) {
#pragma unroll
        for (int c = 0; c < 2; ++c) {
            int i = i0 + ty * 2 + a, j = j0 + tx * 2 + c;
            float vkb = k_base[(size_t)i * W_ + j];
            float out = (j <= i) ? (gate * vkb + alpha * acc[a][c]) : 0.f;
            Mb[(size_t)i * W_ + j] = __float2bfloat16(out);
        }
    }
}

// ---------------------------------------------------------------------------
// shared GEMM helpers
// ---------------------------------------------------------------------------
#define BAR() do { __builtin_amdgcn_sched_barrier(0); \
                   __builtin_amdgcn_s_barrier(); \
                   __builtin_amdgcn_sched_barrier(0); } while (0)

__device__ __forceinline__ void mfma8(const bf16x8 (&fa)[2], const bf16x8 (&fb)[4],
                                      f32x4 (&acc)[2][4]) {
#pragma unroll
    for (int mi = 0; mi < 2; ++mi)
#pragma unroll
        for (int ni = 0; ni < 4; ++ni)
            acc[mi][ni] = __builtin_amdgcn_mfma_f32_16x16x32_bf16(
                fa[mi], fb[ni], acc[mi][ni], 0, 0, 0);
}

__device__ __forceinline__ void readf(const short* At0, const short* Bt0, int slot,
                                      const int (&ao)[2], const int (&bo)[4],
                                      bf16x8 (&fa)[2], bf16x8 (&fb)[4]) {
    const short* Ard = At0 + slot * 4096;
    const short* Brd = Bt0 + slot * 4096;
#pragma unroll
    for (int mi = 0; mi < 2; ++mi) fa[mi] = *(const bf16x8*)&Ard[ao[mi]];
#pragma unroll
    for (int ni = 0; ni < 4; ++ni) fb[ni] = *(const bf16x8*)&Brd[bo[ni]];
}

__device__ __forceinline__ void mfma16(const bf16x8 (&fa)[4], const bf16x8 (&fb)[4],
                                       f32x4 (&acc)[4][4]) {
#pragma unroll
    for (int mi = 0; mi < 4; ++mi)
#pragma unroll
        for (int ni = 0; ni < 4; ++ni)
            acc[mi][ni] = __builtin_amdgcn_mfma_f32_16x16x32_bf16(
                fa[mi], fb[ni], acc[mi][ni], 0, 0, 0);
}

__device__ __forceinline__ void readf4(const short* At0, const short* Bt0, int slot,
                                       const int (&ao)[4], const int (&bo)[4],
                                       bf16x8 (&fa)[4], bf16x8 (&fb)[4]) {
    const short* Ard = At0 + slot * 4096;
    const short* Brd = Bt0 + slot * 4096;
#pragma unroll
    for (int mi = 0; mi < 4; ++mi) fa[mi] = *(const bf16x8*)&Ard[ao[mi]];
#pragma unroll
    for (int ni = 0; ni < 4; ++ni) fb[ni] = *(const bf16x8*)&Brd[bo[ni]];
}

// ---------------------------------------------------------------------------
// OLD 128x128 8-wave MFMA GEMM (r15 5-slot ring) — kept ONLY for step 2
// (N=128, split-K=4). Proven. EPI 5: Cout fp32 partial at z*sC.
// ---------------------------------------------------------------------------
template<int EPI, int SK>
__global__ __launch_bounds__(512, 4)
void mgemm_kernel(const bf16* __restrict__ A, const bf16* __restrict__ Bm,
                  const float* __restrict__ Res, const float* __restrict__ bias,
                  void* __restrict__ Cout,
                  int M, int N, int K,
                  long sA, long sB, long sC, int causal) {
    __shared__ __align__(16) short At[5][128 * 32];
    __shared__ __align__(16) short Bt[5][128 * 32];
    int z = blockIdx.z;
    const bf16* Ab = (SK > 1) ? A : A + (size_t)z * sA;
    const bf16* Bb = (SK > 1) ? Bm : Bm + (size_t)z * sB;
    int kchunk = K / SK;
    int kbeg = (SK > 1) ? z * kchunk : 0;
    int m0 = blockIdx.x * 128, n0 = blockIdx.y * 128;
    int tid = threadIdx.x;
    int lane = tid & 63, wave = tid >> 6;
    int wy = wave >> 1, wx = wave & 1;
    int quad = lane >> 4, l15 = lane & 15;

    f32x4 acc[2][4];
#pragma unroll
    for (int i = 0; i < 2; ++i)
#pragma unroll
        for (int j = 0; j < 4; ++j)
            acc[i][j] = (f32x4){0.f, 0.f, 0.f, 0.f};

    int kend = kbeg + kchunk;
    if (SK == 1 && causal) kend = (m0 + 128 < K) ? m0 + 128 : K;
    int nIter = (kend - kbeg) >> 5;

    int srcChunk = ((lane & 3) ^ ((lane >> 3) & 3)) * 8;
    size_t rowA = (size_t)(m0 + wave * 16 + (lane >> 2)) * K;
    size_t rowB = (size_t)(n0 + wave * 16 + (lane >> 2)) * K;
    const bf16* aP = Ab + rowA + srcChunk + kbeg;
    const bf16* bP = Bb + rowB + srcChunk + kbeg;
    short* aDst = &At[0][0] + wave * 512;
    short* bDst = &Bt[0][0] + wave * 512;

    int rswz = (quad ^ ((l15 >> 1) & 3)) * 8;
    int ao[2], bo[4];
#pragma unroll
    for (int mi = 0; mi < 2; ++mi) ao[mi] = (wy * 32 + mi * 16 + l15) * 32 + rswz;
#pragma unroll
    for (int ni = 0; ni < 4; ++ni) bo[ni] = (wx * 64 + ni * 16 + l15) * 32 + rswz;

#pragma unroll
    for (int p = 0; p < 4; ++p) {
        async16(aP, aDst + p * 4096);
        async16(bP, bDst + p * 4096);
        aP += 32; bP += 32;
    }
    asm volatile("s_waitcnt vmcnt(6)" ::: "memory");
    BAR();

    bf16x8 fa0[2], fb0[4], fa1[2], fb1[4];
    readf(&At[0][0], &Bt[0][0], 0, ao, bo, fa0, fb0);

    int sStage = 4;
    int sPf = 1;
    int nMain = nIter - 4;

    for (int t = 0; t < nMain; t += 2) {
        asm volatile("s_waitcnt vmcnt(4)" ::: "memory");
        BAR();
        async16(aP, aDst + sStage * 4096);
        async16(bP, bDst + sStage * 4096);
        aP += 32; bP += 32;
        sStage = (sStage == 4) ? 0 : sStage + 1;
        mfma8(fa0, fb0, acc);
        readf(&At[0][0], &Bt[0][0], sPf, ao, bo, fa1, fb1);
        sPf = (sPf == 4) ? 0 : sPf + 1;
        asm volatile("s_waitcnt vmcnt(4)" ::: "memory");
        BAR();
        async16(aP, aDst + sStage * 4096);
        async16(bP, bDst + sStage * 4096);
        aP += 32; bP += 32;
        sStage = (sStage == 4) ? 0 : sStage + 1;
        mfma8(fa1, fb1, acc);
        readf(&At[0][0], &Bt[0][0], sPf, ao, bo, fa0, fb0);
        sPf = (sPf == 4) ? 0 : sPf + 1;
    }

    asm volatile("s_waitcnt vmcnt(4)" ::: "memory");
    BAR();
    mfma8(fa0, fb0, acc);
    readf(&At[0][0], &Bt[0][0], sPf, ao, bo, fa1, fb1);
    sPf = (sPf == 4) ? 0 : sPf + 1;

    asm volatile("s_waitcnt vmcnt(2)" ::: "memory");
    BAR();
    mfma8(fa1, fb1, acc);
    readf(&At[0][0], &Bt[0][0], sPf, ao, bo, fa0, fb0);
    sPf = (sPf == 4) ? 0 : sPf + 1;

    asm volatile("s_waitcnt vmcnt(0)" ::: "memory");
    BAR();
    mfma8(fa0, fb0, acc);
    readf(&At[0][0], &Bt[0][0], sPf, ao, bo, fa1, fb1);

    mfma8(fa1, fb1, acc);

#pragma unroll
    for (int ni = 0; ni < 4; ++ni) {
        int col = n0 + wx * 64 + ni * 16 + l15;
        float bv = (EPI == 1 || EPI == 2) ? bias[col] : 0.f;
#pragma unroll
        for (int mi = 0; mi < 2; ++mi) {
            int row0 = m0 + wy * 32 + mi * 16 + quad * 4;
#pragma unroll
            for (int r = 0; r < 4; ++r) {
                size_t idx = (size_t)(row0 + r) * N + col;
                float val = acc[mi][ni][r];
                if constexpr (EPI == 0) {
                    ((bf16*)Cout)[(size_t)z * sC + idx] = __float2bfloat16(val);
                } else if constexpr (EPI == 1) {
                    ((float*)Cout)[idx] = val + bv + Res[idx];
                } else if constexpr (EPI == 2) {
                    val += bv;
                    val = 0.5f * val * (1.f + erff(val * 0.70710678118654752f));
                    ((bf16*)Cout)[idx] = __float2bfloat16(val);
                } else {
                    ((float*)Cout)[(size_t)z * sC + idx] = val;
                }
            }
        }
    }
}

// ---------------------------------------------------------------------------
// 128x128 4-WAVE MFMA GEMM, 3-slot ring (round-18). C[m,n]=sum_k A[m,k]B[n,k]
// *** Round-18 change: 3 BLOCKS/CU. The r15-r17 matrix shows no pipe
// saturated anywhere; per-block wall ~1200cyc vs ~700cyc pipe work ->
// ~500cyc/iter serial stall amortized only by concurrent waves/blocks.
// r15 (16 waves, heavy DS 576cyc) = 1114cyc/blk-iter; r17 (8 waves, light
// DS 384cyc) = 1200. Win condition = light-DS geometry (64x64/wave) AND
// >=12 waves/CU: ring 4->3 slots (48 KB/block) + __launch_bounds__(256,3)
// -> 3 blocks/CU = 12 waves, independent barrier groups overlap (m114).
// Pipeline (top-barrier, stage-first, counted vmcnt, frag prefetch):
//  iter t: STG(t+2)->slot (t+2)%3 | vmcnt(4) [t+1 landed, t+2 in flight] |
//          BAR [publishes t+1]    | mfma(set_t) | prefetch frags(t+1) |
//          lgkmcnt(0)+schedbar    [reads complete before our BAR(t+1)]
// Hazard derivation (3-slot overwrite legality): tile k's frags are read
// during iter k-1 and lgkm0-completed BEFORE that wave arrives at BAR(k)
// (the explicit end-of-iter lgkm0 — without it the compiler defers the
// wait past the barrier and the stage races the in-flight ds_reads).
// Slot k%3 is overwritten by STG(k+3) at the TOP of iter k+1, which every
// wave issues only after passing BAR(k). One-barrier separation restored.
// vmcnt: at iter-t wait, outstanding = tile t+1 (4 loads, staged at t-1)
// + tile t+2 (4, just staged) = 8 -> vmcnt(4) completes exactly tile t+1
// (in-order oldest-first semantics), t+2 stays in flight across the
// barrier (never drain mid-loop). Tail pair: no stage, vmcnt(0) once.
// Staging: wave w stages A rows [w*32,w*32+32), B rows [w*32,w*32+32),
// 2 async16 each; XOR chunk swizzle proven (0 conflicts all rounds).
// Grid XCD-TRANSPOSED: x = M-stripe (swizzle when %8==0), y = N, z = batch.
// EPI 0/1/2 as before. REQUIRES nIter even >= 4 (K mult of 128: all sites).
// ---------------------------------------------------------------------------
template<int EPI>
__global__ __launch_bounds__(256, 3)
void mgemm4_kernel(const bf16* __restrict__ A, const bf16* __restrict__ Bm,
                   const float* __restrict__ Res, const float* __restrict__ bias,
                   void* __restrict__ Cout,
                   int M, int N, int K, long sA, long sB, long sC, int causal) {
    __shared__ __align__(16) short At[3][128 * 32];   // 3 x 8 KB
    __shared__ __align__(16) short Bt[3][128 * 32];   // 3 x 8 KB
    int z = blockIdx.z;
    const bf16* Ab = A + (size_t)z * sA;
    const bf16* Bb = Bm + (size_t)z * sB;

    int bx = blockIdx.x, gx = gridDim.x;
    if ((gx & 7) == 0) { int cpx = gx >> 3; bx = (bx & 7) * cpx + (bx >> 3); }
    int m0 = bx * 128, n0 = blockIdx.y * 128;

    int tid = threadIdx.x;
    int lane = tid & 63, wave = tid >> 6;           // 4 waves
    int wm = wave >> 1, wn = wave & 1;              // 2M x 2N, 64x64 each
    int quad = lane >> 4, l15 = lane & 15;

    f32x4 acc[4][4];
#pragma unroll
    for (int i = 0; i < 4; ++i)
#pragma unroll
        for (int j = 0; j < 4; ++j)
            acc[i][j] = (f32x4){0.f, 0.f, 0.f, 0.f};

    int kend = causal ? ((m0 + 128 < K) ? m0 + 128 : K) : K;
    int nIter = kend >> 5;                          // even, >= 4

    int srcChunk = ((lane & 3) ^ ((lane >> 3) & 3)) * 8;
    const bf16* aP0 = Ab + (size_t)(m0 + wave * 32 + (lane >> 2)) * K + srcChunk;
    const bf16* aP1 = aP0 + (size_t)16 * K;
    const bf16* bP0 = Bb + (size_t)(n0 + wave * 32 + (lane >> 2)) * K + srcChunk;
    const bf16* bP1 = bP0 + (size_t)16 * K;
    short* aDst = &At[0][0] + wave * 1024;          // 32 rows x 32 shorts
    short* bDst = &Bt[0][0] + wave * 1024;

    int rswz = (quad ^ ((l15 >> 1) & 3)) * 8;
    int ao[4], bo[4];
#pragma unroll
    for (int mi = 0; mi < 4; ++mi) ao[mi] = (wm * 64 + mi * 16 + l15) * 32 + rswz;
#pragma unroll
    for (int ni = 0; ni < 4; ++ni) bo[ni] = (wn * 64 + ni * 16 + l15) * 32 + rswz;

#define STG3(slot) do { \
        short* _a = aDst + (slot) * 4096; \
        short* _b = bDst + (slot) * 4096; \
        async16(aP0, _a); async16(aP1, _a + 512); \
        async16(bP0, _b); async16(bP1, _b + 512); \
        aP0 += 32; aP1 += 32; bP0 += 32; bP1 += 32; \
    } while (0)
#define LGKM0() do { asm volatile("s_waitcnt lgkmcnt(0)" ::: "memory"); \
                     __builtin_amdgcn_sched_barrier(0); } while (0)

    // prologue: stage tiles 0,1 -> slots 0,1; tile 0 landed (1 in flight);
    // publish; prefetch frags 0; lgkm0 (complete before BAR of iter 0).
    STG3(0); STG3(1);
    asm volatile("s_waitcnt vmcnt(4)" ::: "memory");
    BAR();

    bf16x8 fa0[4], fb0[4], fa1[4], fb1[4];
    readf4(&At[0][0], &Bt[0][0], 0, ao, bo, fa0, fb0);
    LGKM0();

    int sStage = 2;   // slot for next staged tile (tile 2)
    int sPf = 1;      // slot of next prefetched tile (tile 1)
    int nMain = nIter - 2;   // even >= 2

    for (int t = 0; t < nMain; t += 2) {
        // ---- iter t (set0) ----
        STG3(sStage); sStage = (sStage == 2) ? 0 : sStage + 1;
        asm volatile("s_waitcnt vmcnt(4)" ::: "memory");
        BAR();
        mfma16(fa0, fb0, acc);
        readf4(&At[0][0], &Bt[0][0], sPf, ao, bo, fa1, fb1);
        sPf = (sPf == 2) ? 0 : sPf + 1;
        LGKM0();
        // ---- iter t+1 (set1) ----
        STG3(sStage); sStage = (sStage == 2) ? 0 : sStage + 1;
        asm volatile("s_waitcnt vmcnt(4)" ::: "memory");
        BAR();
        mfma16(fa1, fb1, acc);
        readf4(&At[0][0], &Bt[0][0], sPf, ao, bo, fa0, fb0);
        sPf = (sPf == 2) ? 0 : sPf + 1;
        LGKM0();
    }

    // ---- tail: iters nIter-2 (set0), nIter-1 (set1); no stages left ----
    asm volatile("s_waitcnt vmcnt(0)" ::: "memory");
    BAR();
    mfma16(fa0, fb0, acc);
    readf4(&At[0][0], &Bt[0][0], sPf, ao, bo, fa1, fb1);
    mfma16(fa1, fb1, acc);
#undef STG3
#undef LGKM0

    // ---- epilogue ----
#pragma unroll
    for (int ni = 0; ni < 4; ++ni) {
        int col = n0 + wn * 64 + ni * 16 + l15;
        float bv = (EPI == 1 || EPI == 2) ? bias[col] : 0.f;
#pragma unroll
        for (int mi = 0; mi < 4; ++mi) {
            int row0 = m0 + wm * 64 + mi * 16 + quad * 4;
#pragma unroll
            for (int r = 0; r < 4; ++r) {
                size_t idx = (size_t)(row0 + r) * N + col;
                float val = acc[mi][ni][r];
                if constexpr (EPI == 0) {
                    ((bf16*)Cout)[(size_t)z * sC + idx] = __float2bfloat16(val);
                } else if constexpr (EPI == 1) {
                    ((float*)Cout)[idx] = val + bv + Res[idx];
                } else {
                    val += bv;
                    val = 0.5f * val * (1.f + erff(val * 0.70710678118654752f));
                    ((bf16*)Cout)[idx] = __float2bfloat16(val);
                }
            }
        }
    }
}

// ---------------------------------------------------------------------------
// Workspace (peak 62 MB):
//   [0,16)  : hnorm bf16 -> attn bf16 (step4 out) -> mnorm bf16 (step6 out)
//   [16,18) : uvT bf16 (dead after step 2) -> qg fp32 (written step 2b)
//   [18,20) : kg fp32
//   [20,36) : hnormT bf16            -+ tbuf bf16 [20,52) after step 4
//   [36,52) : qkraw fp32 4x4MB split-K partials (dead after 2b) -> Mbuf bf16
//   [52,54) : proj_w bf16   [54,58): up_w bf16   [58,62): down_w bf16
//   h1 lives in d_out (fp32); step 8 does same-index RMW (alias-safe).
// ---------------------------------------------------------------------------
extern "C" void kernel_launch(void* const* d_in, const int* in_sizes, int n_in,
                              void* d_out, int out_size, void* d_ws, size_t ws_size,
                              hipStream_t stream) {
    const float* h           = (const float*)d_in[0];
    const float* k_base      = (const float*)d_in[1];
    const float* decay_logit = (const float*)d_in[2];
    const float* gate_logit  = (const float*)d_in[3];
    const float* alpha_logit = (const float*)d_in[4];
    const float* u           = (const float*)d_in[5];
    const float* v           = (const float*)d_in[6];
    const float* proj_w      = (const float*)d_in[7];
    const float* proj_b      = (const float*)d_in[8];
    const float* norm1_scale = (const float*)d_in[9];
    const float* norm2_scale = (const float*)d_in[10];
    const float* up_w        = (const float*)d_in[11];
    const float* up_b        = (const float*)d_in[12];
    const float* down_w      = (const float*)d_in[13];
    const float* down_b      = (const float*)d_in[14];

    const size_t MB = 1048576;
    char* ws = (char*)d_ws;
    bf16*  hnorm   = (bf16*)(ws);                  // 16 MB
    bf16*  uvT     = (bf16*)(ws + 16 * MB);        // 256 KB (dead after step 2)
    float* qg      = (float*)(ws + 16 * MB);       //  2 MB (written step 2b)
    float* kg      = (float*)(ws + 18 * MB);       //  2 MB
    bf16*  hnormT  = (bf16*)(ws + 20 * MB);        // 16 MB
    float* qkraw   = (float*)(ws + 36 * MB);       // 16 MB partials (pre-buildM)
    bf16*  Mbuf    = (bf16*)(ws + 36 * MB);        // 16 MB (step 3 out)
    bf16*  proj_wb = (bf16*)(ws + 52 * MB);        //  2 MB
    bf16*  up_wb   = (bf16*)(ws + 54 * MB);        //  4 MB
    bf16*  down_wb = (bf16*)(ws + 58 * MB);        //  4 MB
    bf16*  attn    = hnorm;                        // [0,16) after qk GEMM
    bf16*  mnorm   = hnorm;
    bf16*  tbuf    = hnormT;                       // [20,52) after step 4
    float* h1      = (float*)d_out;

    // 0. weight conversions (single launch) + uvT
    convert3_kernel<<<5 * D_ * D_ / 2048, 256, 0, stream>>>(
        proj_w, up_w, down_w, proj_wb, up_wb, down_wb);
    uvT_kernel<<<dim3(D_ / 64, 1, 2), 256, 0, stream>>>(u, v, uvT);

    // 1. h_norm = rmsnorm(h, norm1_scale)
    rmsnorm_kernel<<<B_ * W_, 256, 0, stream>>>(h, norm1_scale, hnorm);

    // 1b. hnormT[b][d][j] = hnorm[b][j][d]
    transpose_kernel<<<dim3(W_ / 64, D_ / 64, B_), 256, 0, stream>>>(hnorm, hnormT);

    // 2. qkraw[z] = hnorm @ [u|v] K-chunk z (deterministic split-K=4)
    mgemm_kernel<5, 4><<<dim3(B_ * W_ / 128, 1, 4), 512, 0, stream>>>(
        hnorm, uvT, nullptr, nullptr, qkraw, B_ * W_, 128, D_,
        0, 0, (long)B_ * W_ * 128, 0);

    // 2b. sum partials, l2norm halves, gamma^{+/-i} -> qg, kg (fp32)
    qk_epilogue_kernel<<<B_ * W_, 128, 0, stream>>>(qkraw, decay_logit, qg, kg);

    // 3. M = causal * (gate*k_base + alpha*scores)
    buildM_kernel<<<dim3(W_ / 32, W_ / 32, B_), dim3(16, 16), 0, stream>>>(
        qg, kg, k_base, gate_logit, alpha_logit, Mbuf);

    // 4. attn = M @ hnorm  (B = hnormT, batched via z, causal k-trunc)
    mgemm4_kernel<0><<<dim3(W_ / 128, D_ / 128, B_), 256, 0, stream>>>(
        Mbuf, hnormT, nullptr, nullptr, attn, W_, D_, W_,
        (long)W_ * W_, (long)W_ * D_, (long)W_ * D_, 1);

    // 5. h1 = h + attn @ proj_w^T + proj_b   -> d_out (fp32)
    mgemm4_kernel<1><<<dim3(B_ * W_ / 128, D_ / 128, 1), 256, 0, stream>>>(
        attn, proj_wb, h, proj_b, h1, B_ * W_, D_, D_, 0, 0, 0, 0);

    // 6. mnorm = rmsnorm(h1, norm2_scale)
    rmsnorm_kernel<<<B_ * W_, 256, 0, stream>>>(h1, norm2_scale, mnorm);

    // 7. t = gelu(mnorm @ up_w^T + up_b)     -> tbuf (bf16)
    mgemm4_kernel<2><<<dim3(B_ * W_ / 128, 2 * D_ / 128, 1), 256, 0, stream>>>(
        mnorm, up_wb, nullptr, up_b, tbuf, B_ * W_, 2 * D_, D_, 0, 0, 0, 0);

    // 8. out = h1 + t @ down_w^T + down_b  (h1 aliases d_out, same-idx RMW)
    mgemm4_kernel<1><<<dim3(B_ * W_ / 128, D_ / 128, 1), 256, 0, stream>>>(
        tbuf, down_wb, h1, down_b, (float*)d_out, B_ * W_, D_, 2 * D_, 0, 0, 0, 0);
}

// Round 7
// 329.805 us; speedup vs baseline: 1.1322x; 1.0645x over previous
//
#include <hip/hip_runtime.h>
#include <hip/hip_bf16.h>
#include <math.h>

#define B_ 8
#define W_ 1024
#define D_ 1024
#define R_ 64

typedef __hip_bfloat16 bf16;
typedef __attribute__((ext_vector_type(8))) short bf16x8;   // MFMA A/B frag (4 VGPRs)
typedef __attribute__((ext_vector_type(4))) short short4v;  // 4 bf16 store
typedef __attribute__((ext_vector_type(4))) float f32x4;    // MFMA C/D frag

__device__ __forceinline__ float tof(bf16 x) { return __bfloat162float(x); }
__device__ __forceinline__ short f2bs(float f) {
    bf16 b = __float2bfloat16(f);
    return *(short*)&b;
}

// async global->LDS, 16 bytes/lane; LDS dest = wave-uniform base + lane*16
__device__ __forceinline__ void async16(const void* g, void* l) {
    __builtin_amdgcn_global_load_lds(
        (const __attribute__((address_space(1))) unsigned int*)g,
        (__attribute__((address_space(3))) unsigned int*)l,
        16, 0, 0);
}

// ---------------------------------------------------------------------------
// RMSNorm body (float4-vectorized, round-19): row of D_=1024, 256 threads.
// ---------------------------------------------------------------------------
__device__ __forceinline__ void rmsnorm_body(const float* __restrict__ src,
                                             const float* __restrict__ scale,
                                             bf16* __restrict__ dst, int row,
                                             float* red, float* invs) {
    const float4* x = (const float4*)(src + (size_t)row * D_);
    bf16* y = dst + (size_t)row * D_;
    int t = threadIdx.x;
    float4 v = x[t];
    float ss = v.x * v.x + v.y * v.y + v.z * v.z + v.w * v.w;
#pragma unroll
    for (int off = 32; off; off >>= 1) ss += __shfl_down(ss, off, 64);
    int lane = t & 63, wid = t >> 6;
    if (lane == 0) red[wid] = ss;
    __syncthreads();
    if (t == 0) {
        float s = red[0] + red[1] + red[2] + red[3];
        *invs = rsqrtf(s / (float)D_ + 1e-8f);
    }
    __syncthreads();
    float inv = *invs;
    float4 s4 = ((const float4*)scale)[t];
    short4v o;
    o[0] = f2bs(v.x * inv * s4.x);
    o[1] = f2bs(v.y * inv * s4.y);
    o[2] = f2bs(v.z * inv * s4.z);
    o[3] = f2bs(v.w * inv * s4.w);
    *(short4v*)&y[t * 4] = o;
}

__global__ __launch_bounds__(256)
void rmsnorm_kernel(const float* __restrict__ src, const float* __restrict__ scale,
                    bf16* __restrict__ dst) {
    __shared__ float red[4];
    __shared__ float invs;
    rmsnorm_body(src, scale, dst, blockIdx.x, red, &invs);
}

// ---------------------------------------------------------------------------
// prep_kernel (round-19): ONE launch fusing three independent prep ops.
//  blocks [0, 2560)      : fp32->bf16 convert of proj/up/down weights
//  blocks [2560, 2592)   : uvT build ([128][1024] bf16 from u,v [1024][64])
//  blocks [2592, 10784)  : rmsnorm(h) -> hnorm
// Saves 2 launch gaps; all three touch disjoint memory.
// ---------------------------------------------------------------------------
__global__ __launch_bounds__(256)
void prep_kernel(const float* __restrict__ proj, const float* __restrict__ up,
                 const float* __restrict__ down,
                 bf16* __restrict__ projb, bf16* __restrict__ upb,
                 bf16* __restrict__ downb,
                 const float* __restrict__ u, const float* __restrict__ v,
                 bf16* __restrict__ uvT,
                 const float* __restrict__ h, const float* __restrict__ n1,
                 bf16* __restrict__ hnorm) {
    __shared__ float Ts[64][65];
    __shared__ float red[4];
    __shared__ float invs;
    int bid = blockIdx.x;
    int tid = threadIdx.x;
    if (bid < 2560) {
        // ---- convert3 ----
        size_t idx = ((size_t)bid * 256 + tid) * 8;
        const size_t DD = (size_t)D_ * D_;
        const float* src; bf16* dst; size_t off;
        if (idx < DD)          { src = proj; dst = projb; off = idx; }
        else if (idx < 3 * DD) { src = up;   dst = upb;   off = idx - DD; }
        else                   { src = down; dst = downb; off = idx - 3 * DD; }
        float4 f0 = *(const float4*)(src + off);
        float4 f1 = *(const float4*)(src + off + 4);
        bf16x8 p;
        p[0] = f2bs(f0.x); p[1] = f2bs(f0.y); p[2] = f2bs(f0.z); p[3] = f2bs(f0.w);
        p[4] = f2bs(f1.x); p[5] = f2bs(f1.y); p[6] = f2bs(f1.z); p[7] = f2bs(f1.w);
        *(bf16x8*)(dst + off) = p;
    } else if (bid < 2592) {
        // ---- uvT ----
        int lb = bid - 2560;
        int g = lb >> 4;
        int d0 = (lb & 15) * 64;
        const float* src = g ? v : u;
#pragma unroll
        for (int e = 0; e < 16; ++e) {
            int idx = tid + e * 256;
            int drow = idx >> 6, rcol = idx & 63;
            Ts[drow][rcol] = src[(size_t)(d0 + drow) * 64 + rcol];
        }
        __syncthreads();
#pragma unroll
        for (int e = 0; e < 16; ++e) {
            int idx = tid + e * 256;
            int orow = idx >> 6, ocol = idx & 63;
            uvT[(size_t)(g * 64 + orow) * D_ + d0 + ocol] = __float2bfloat16(Ts[ocol][orow]);
        }
    } else {
        // ---- rmsnorm(h) ----
        rmsnorm_body(h, n1, hnorm, bid - 2592, red, &invs);
    }
}

// ---------------------------------------------------------------------------
// 64x64 LDS-tiled transpose: src[b][j][d] -> dst[b][d][j]  (bf16)
// ---------------------------------------------------------------------------
__global__ __launch_bounds__(256)
void transpose_kernel(const bf16* __restrict__ src, bf16* __restrict__ dst) {
    int b = blockIdx.z;
    int j0 = blockIdx.x * 64, d0 = blockIdx.y * 64;
    __shared__ short Ts[64][72];
    const bf16* S = src + (size_t)b * W_ * D_;
    bf16* Dd = dst + (size_t)b * W_ * D_;
    int tid = threadIdx.x;
    int r = tid >> 3, c = (tid & 7) * 8;
#pragma unroll
    for (int p = 0; p < 2; ++p) {
        int j = r + p * 32;
        bf16x8 vv = *(const bf16x8*)&S[(size_t)(j0 + j) * D_ + d0 + c];
#pragma unroll
        for (int e = 0; e < 8; ++e) Ts[j][c + e] = vv[e];
    }
    __syncthreads();
#pragma unroll
    for (int p = 0; p < 2; ++p) {
        int d = r + p * 32;
        bf16x8 vv;
#pragma unroll
        for (int e = 0; e < 8; ++e) vv[e] = Ts[c + e][d];
        *(bf16x8*)&Dd[(size_t)(d0 + d) * W_ + j0 + c] = vv;
    }
}

// ---------------------------------------------------------------------------
// qk epilogue: sum SK=4 fp32 partials, l2norm halves, gamma^{+/-i} -> qg, kg.
// ---------------------------------------------------------------------------
__global__ __launch_bounds__(128)
void qk_epilogue_kernel(const float* __restrict__ qkraw,
                        const float* __restrict__ decay_logit,
                        float* __restrict__ qg, float* __restrict__ kg) {
    int row = blockIdx.x;          // b*W + i
    int i = row & (W_ - 1);
    int t = threadIdx.x;
    int r = t & 63;
    bool isK = t >= 64;
    const size_t PS = (size_t)B_ * W_ * 128;   // partial stride
    size_t off = (size_t)row * 128 + t;
    float val = qkraw[off] + qkraw[PS + off] + qkraw[2 * PS + off] + qkraw[3 * PS + off];
    float sq = val * val;
#pragma unroll
    for (int o = 32; o; o >>= 1) sq += __shfl_xor(sq, o, 64);
    val = val / fmaxf(sqrtf(sq), 1e-8f);

    float dl = decay_logit[r];
    float gamma = 0.15f + 0.85f * (1.f / (1.f + expf(-dl)));
    float lg = logf(gamma);
    float e = isK ? expf(-(float)i * lg) : expf((float)i * lg);
    float o = val * e;
    if (isK) kg[(size_t)row * R_ + r] = o;
    else     qg[(size_t)row * R_ + r] = o;
}

// ---------------------------------------------------------------------------
// buildM v2 (round-19): M[b,i,j] = (j<=i) ? gate*k_base + alpha*qg.kg : 0
// 64x64 tiles, 256 thr, 4x4/thread, float4 LDS reads (8 b128/wave/k-quad
// vs old 256 scalar ds_read_b32/wave — the old kernel was ~20us of scalar
// LDS). SKIP-WITHOUT-WRITE tiles with tj64 > (ti64|1): step 4's causal
// k-truncation (kend = m0+128) provably never reads M[:, j >= m0+128],
// and rows m0..m0+127 have ti64 in {m0/64, m0/64+1} -> read cols only in
// tj64 <= (ti64|1). Removes ~8 MB of zero writes + ~40% of blocks.
// Zero-fill only the read-but-above-diagonal tile (ti64 even, tj64=ti64+1).
// ---------------------------------------------------------------------------
__global__ __launch_bounds__(256)
void buildM_kernel(const float* __restrict__ qg, const float* __restrict__ kg,
                   const float* __restrict__ k_base,
                   const float* __restrict__ gate_logit,
                   const float* __restrict__ alpha_logit,
                   bf16* __restrict__ M) {
    int b = blockIdx.z;
    int ti = blockIdx.y, tj = blockIdx.x;   // 64-row/col tiles
    if (tj > (ti | 1)) return;              // never read by step 4: no write
    int i0 = ti * 64, j0 = tj * 64;
    bf16* Mb = M + (size_t)b * W_ * W_;
    int tid = threadIdx.x;

    if (tj > ti) {
        // entire tile strictly above diagonal but read: zeros (16 bf16/thr)
        int row = tid >> 2, c0 = (tid & 3) * 16;
        bf16x8 z;
#pragma unroll
        for (int e = 0; e < 8; ++e) z[e] = 0;
        *(bf16x8*)&Mb[(size_t)(i0 + row) * W_ + j0 + c0] = z;
        *(bf16x8*)&Mb[(size_t)(i0 + row) * W_ + j0 + c0 + 8] = z;
        return;
    }

    __shared__ float Qs[64][68];
    __shared__ float Ks[64][68];
#pragma unroll
    for (int e = 0; e < 4; ++e) {
        int idx = tid + e * 256;            // float4 slot 0..1023
        int row = idx >> 4, c4 = (idx & 15) * 4;
        *(float4*)&Qs[row][c4] = *(const float4*)&qg[((size_t)b * W_ + i0 + row) * R_ + c4];
        *(float4*)&Ks[row][c4] = *(const float4*)&kg[((size_t)b * W_ + j0 + row) * R_ + c4];
    }
    __syncthreads();

    int tx = tid & 15, ty = tid >> 4;       // 4 cols, 4 rows per thread
    float acc[4][4] = {};
#pragma unroll 4
    for (int rq = 0; rq < 16; ++rq) {
        float4 qa[4], kb[4];
#pragma unroll
        for (int a = 0; a < 4; ++a) qa[a] = *(const float4*)&Qs[ty * 4 + a][rq * 4];
#pragma unroll
        for (int c = 0; c < 4; ++c) kb[c] = *(const float4*)&Ks[tx * 4 + c][rq * 4];
#pragma unroll
        for (int a = 0; a < 4; ++a)
#pragma unroll
            for (int c = 0; c < 4; ++c)
                acc[a][c] += qa[a].x * kb[c].x + qa[a].y * kb[c].y
                           + qa[a].z * kb[c].z + qa[a].w * kb[c].w;
    }

    float gate  = 1.f / (1.f + expf(-(*gate_logit)));
    float alpha = 1.f / (1.f + expf(-(*alpha_logit)));  // ALPHA_CAP = 1
#pragma unroll
    for (int a = 0; a < 4; ++a) {
        int i = i0 + ty * 4 + a;
        int jb = j0 + tx * 4;
        float4 vkb = *(const float4*)&k_base[(size_t)i * W_ + jb];
        short4v o;
        o[0] = (jb + 0 <= i) ? f2bs(gate * vkb.x + alpha * acc[a][0]) : (short)0;
        o[1] = (jb + 1 <= i) ? f2bs(gate * vkb.y + alpha * acc[a][1]) : (short)0;
        o[2] = (jb + 2 <= i) ? f2bs(gate * vkb.z + alpha * acc[a][2]) : (short)0;
        o[3] = (jb + 3 <= i) ? f2bs(gate * vkb.w + alpha * acc[a][3]) : (short)0;
        *(short4v*)&Mb[(size_t)i * W_ + jb] = o;
    }
}

// ---------------------------------------------------------------------------
// shared GEMM helpers
// ---------------------------------------------------------------------------
#define BAR() do { __builtin_amdgcn_sched_barrier(0); \
                   __builtin_amdgcn_s_barrier(); \
                   __builtin_amdgcn_sched_barrier(0); } while (0)

__device__ __forceinline__ void mfma8(const bf16x8 (&fa)[2], const bf16x8 (&fb)[4],
                                      f32x4 (&acc)[2][4]) {
#pragma unroll
    for (int mi = 0; mi < 2; ++mi)
#pragma unroll
        for (int ni = 0; ni < 4; ++ni)
            acc[mi][ni] = __builtin_amdgcn_mfma_f32_16x16x32_bf16(
                fa[mi], fb[ni], acc[mi][ni], 0, 0, 0);
}

__device__ __forceinline__ void readf(const short* At0, const short* Bt0, int slot,
                                      const int (&ao)[2], const int (&bo)[4],
                                      bf16x8 (&fa)[2], bf16x8 (&fb)[4]) {
    const short* Ard = At0 + slot * 4096;
    const short* Brd = Bt0 + slot * 4096;
#pragma unroll
    for (int mi = 0; mi < 2; ++mi) fa[mi] = *(const bf16x8*)&Ard[ao[mi]];
#pragma unroll
    for (int ni = 0; ni < 4; ++ni) fb[ni] = *(const bf16x8*)&Brd[bo[ni]];
}

// ---------------------------------------------------------------------------
// 128x128 8-wave MFMA GEMM (r15 5-slot ring, depth-3 counted vmcnt + frag
// prefetch) — the PROVEN best config across r13-r18 (59us step-7, MfmaUtil
// 24). Round-19: restored at ALL GEMM sites; r16/r17/r18 variants (bigger
// per-wave tiles / other residencies) all regressed and are deleted.
// EPI 0: bf16 = acc (batched via z*sC) | EPI 1: fp32 = acc+bias+Res |
// EPI 2: bf16 = gelu(acc+bias)         | EPI 5: fp32 partial at z*sC.
// ---------------------------------------------------------------------------
template<int EPI, int SK>
__global__ __launch_bounds__(512, 4)
void mgemm_kernel(const bf16* __restrict__ A, const bf16* __restrict__ Bm,
                  const float* __restrict__ Res, const float* __restrict__ bias,
                  void* __restrict__ Cout,
                  int M, int N, int K,
                  long sA, long sB, long sC, int causal) {
    __shared__ __align__(16) short At[5][128 * 32];
    __shared__ __align__(16) short Bt[5][128 * 32];
    int z = blockIdx.z;
    const bf16* Ab = (SK > 1) ? A : A + (size_t)z * sA;
    const bf16* Bb = (SK > 1) ? Bm : Bm + (size_t)z * sB;
    int kchunk = K / SK;
    int kbeg = (SK > 1) ? z * kchunk : 0;
    int m0 = blockIdx.x * 128, n0 = blockIdx.y * 128;
    int tid = threadIdx.x;
    int lane = tid & 63, wave = tid >> 6;
    int wy = wave >> 1, wx = wave & 1;
    int quad = lane >> 4, l15 = lane & 15;

    f32x4 acc[2][4];
#pragma unroll
    for (int i = 0; i < 2; ++i)
#pragma unroll
        for (int j = 0; j < 4; ++j)
            acc[i][j] = (f32x4){0.f, 0.f, 0.f, 0.f};

    int kend = kbeg + kchunk;
    if (SK == 1 && causal) kend = (m0 + 128 < K) ? m0 + 128 : K;
    int nIter = (kend - kbeg) >> 5;

    int srcChunk = ((lane & 3) ^ ((lane >> 3) & 3)) * 8;
    size_t rowA = (size_t)(m0 + wave * 16 + (lane >> 2)) * K;
    size_t rowB = (size_t)(n0 + wave * 16 + (lane >> 2)) * K;
    const bf16* aP = Ab + rowA + srcChunk + kbeg;
    const bf16* bP = Bb + rowB + srcChunk + kbeg;
    short* aDst = &At[0][0] + wave * 512;
    short* bDst = &Bt[0][0] + wave * 512;

    int rswz = (quad ^ ((l15 >> 1) & 3)) * 8;
    int ao[2], bo[4];
#pragma unroll
    for (int mi = 0; mi < 2; ++mi) ao[mi] = (wy * 32 + mi * 16 + l15) * 32 + rswz;
#pragma unroll
    for (int ni = 0; ni < 4; ++ni) bo[ni] = (wx * 64 + ni * 16 + l15) * 32 + rswz;

#pragma unroll
    for (int p = 0; p < 4; ++p) {
        async16(aP, aDst + p * 4096);
        async16(bP, bDst + p * 4096);
        aP += 32; bP += 32;
    }
    asm volatile("s_waitcnt vmcnt(6)" ::: "memory");
    BAR();

    bf16x8 fa0[2], fb0[4], fa1[2], fb1[4];
    readf(&At[0][0], &Bt[0][0], 0, ao, bo, fa0, fb0);

    int sStage = 4;
    int sPf = 1;
    int nMain = nIter - 4;

    for (int t = 0; t < nMain; t += 2) {
        asm volatile("s_waitcnt vmcnt(4)" ::: "memory");
        BAR();
        async16(aP, aDst + sStage * 4096);
        async16(bP, bDst + sStage * 4096);
        aP += 32; bP += 32;
        sStage = (sStage == 4) ? 0 : sStage + 1;
        mfma8(fa0, fb0, acc);
        readf(&At[0][0], &Bt[0][0], sPf, ao, bo, fa1, fb1);
        sPf = (sPf == 4) ? 0 : sPf + 1;
        asm volatile("s_waitcnt vmcnt(4)" ::: "memory");
        BAR();
        async16(aP, aDst + sStage * 4096);
        async16(bP, bDst + sStage * 4096);
        aP += 32; bP += 32;
        sStage = (sStage == 4) ? 0 : sStage + 1;
        mfma8(fa1, fb1, acc);
        readf(&At[0][0], &Bt[0][0], sPf, ao, bo, fa0, fb0);
        sPf = (sPf == 4) ? 0 : sPf + 1;
    }

    asm volatile("s_waitcnt vmcnt(4)" ::: "memory");
    BAR();
    mfma8(fa0, fb0, acc);
    readf(&At[0][0], &Bt[0][0], sPf, ao, bo, fa1, fb1);
    sPf = (sPf == 4) ? 0 : sPf + 1;

    asm volatile("s_waitcnt vmcnt(2)" ::: "memory");
    BAR();
    mfma8(fa1, fb1, acc);
    readf(&At[0][0], &Bt[0][0], sPf, ao, bo, fa0, fb0);
    sPf = (sPf == 4) ? 0 : sPf + 1;

    asm volatile("s_waitcnt vmcnt(0)" ::: "memory");
    BAR();
    mfma8(fa0, fb0, acc);
    readf(&At[0][0], &Bt[0][0], sPf, ao, bo, fa1, fb1);

    mfma8(fa1, fb1, acc);

#pragma unroll
    for (int ni = 0; ni < 4; ++ni) {
        int col = n0 + wx * 64 + ni * 16 + l15;
        float bv = (EPI == 1 || EPI == 2) ? bias[col] : 0.f;
#pragma unroll
        for (int mi = 0; mi < 2; ++mi) {
            int row0 = m0 + wy * 32 + mi * 16 + quad * 4;
#pragma unroll
            for (int r = 0; r < 4; ++r) {
                size_t idx = (size_t)(row0 + r) * N + col;
                float val = acc[mi][ni][r];
                if constexpr (EPI == 0) {
                    ((bf16*)Cout)[(size_t)z * sC + idx] = __float2bfloat16(val);
                } else if constexpr (EPI == 1) {
                    ((float*)Cout)[idx] = val + bv + Res[idx];
                } else if constexpr (EPI == 2) {
                    val += bv;
                    val = 0.5f * val * (1.f + erff(val * 0.70710678118654752f));
                    ((bf16*)Cout)[idx] = __float2bfloat16(val);
                } else {
                    ((float*)Cout)[(size_t)z * sC + idx] = val;
                }
            }
        }
    }
}

// ---------------------------------------------------------------------------
// Workspace (peak 62 MB):
//   [0,16)  : hnorm bf16 -> attn bf16 (step4 out) -> mnorm bf16 (step6 out)
//   [16,18) : uvT bf16 (dead after step 2) -> qg fp32 (written step 2b)
//   [18,20) : kg fp32
//   [20,36) : hnormT bf16            -+ tbuf bf16 [20,52) after step 4
//   [36,52) : qkraw fp32 4x4MB split-K partials (dead after 2b) -> Mbuf bf16
//   [52,54) : proj_w bf16   [54,58): up_w bf16   [58,62): down_w bf16
//   h1 lives in d_out (fp32); step 8 does same-index RMW (alias-safe).
// ---------------------------------------------------------------------------
extern "C" void kernel_launch(void* const* d_in, const int* in_sizes, int n_in,
                              void* d_out, int out_size, void* d_ws, size_t ws_size,
                              hipStream_t stream) {
    const float* h           = (const float*)d_in[0];
    const float* k_base      = (const float*)d_in[1];
    const float* decay_logit = (const float*)d_in[2];
    const float* gate_logit  = (const float*)d_in[3];
    const float* alpha_logit = (const float*)d_in[4];
    const float* u           = (const float*)d_in[5];
    const float* v           = (const float*)d_in[6];
    const float* proj_w      = (const float*)d_in[7];
    const float* proj_b      = (const float*)d_in[8];
    const float* norm1_scale = (const float*)d_in[9];
    const float* norm2_scale = (const float*)d_in[10];
    const float* up_w        = (const float*)d_in[11];
    const float* up_b        = (const float*)d_in[12];
    const float* down_w      = (const float*)d_in[13];
    const float* down_b      = (const float*)d_in[14];

    const size_t MB = 1048576;
    char* ws = (char*)d_ws;
    bf16*  hnorm   = (bf16*)(ws);                  // 16 MB
    bf16*  uvT     = (bf16*)(ws + 16 * MB);        // 256 KB (dead after step 2)
    float* qg      = (float*)(ws + 16 * MB);       //  2 MB (written step 2b)
    float* kg      = (float*)(ws + 18 * MB);       //  2 MB
    bf16*  hnormT  = (bf16*)(ws + 20 * MB);        // 16 MB
    float* qkraw   = (float*)(ws + 36 * MB);       // 16 MB partials (pre-buildM)
    bf16*  Mbuf    = (bf16*)(ws + 36 * MB);        // 16 MB (step 3 out)
    bf16*  proj_wb = (bf16*)(ws + 52 * MB);        //  2 MB
    bf16*  up_wb   = (bf16*)(ws + 54 * MB);        //  4 MB
    bf16*  down_wb = (bf16*)(ws + 58 * MB);        //  4 MB
    bf16*  attn    = hnorm;                        // [0,16) after qk GEMM
    bf16*  mnorm   = hnorm;
    bf16*  tbuf    = hnormT;                       // [20,52) after step 4
    float* h1      = (float*)d_out;

    // 0+1. fused prep: weight converts + uvT + rmsnorm(h) in ONE launch
    prep_kernel<<<2560 + 32 + B_ * W_, 256, 0, stream>>>(
        proj_w, up_w, down_w, proj_wb, up_wb, down_wb,
        u, v, uvT, h, norm1_scale, hnorm);

    // 1b. hnormT[b][d][j] = hnorm[b][j][d]
    transpose_kernel<<<dim3(W_ / 64, D_ / 64, B_), 256, 0, stream>>>(hnorm, hnormT);

    // 2. qkraw[z] = hnorm @ [u|v] K-chunk z (deterministic split-K=4)
    mgemm_kernel<5, 4><<<dim3(B_ * W_ / 128, 1, 4), 512, 0, stream>>>(
        hnorm, uvT, nullptr, nullptr, qkraw, B_ * W_, 128, D_,
        0, 0, (long)B_ * W_ * 128, 0);

    // 2b. sum partials, l2norm halves, gamma^{+/-i} -> qg, kg (fp32)
    qk_epilogue_kernel<<<B_ * W_, 128, 0, stream>>>(qkraw, decay_logit, qg, kg);

    // 3. M = causal * (gate*k_base + alpha*scores)  [64x64 tiles, skip-unread]
    buildM_kernel<<<dim3(W_ / 64, W_ / 64, B_), 256, 0, stream>>>(
        qg, kg, k_base, gate_logit, alpha_logit, Mbuf);

    // 4. attn = M @ hnorm  (B = hnormT, batched via z, causal k-trunc)
    mgemm_kernel<0, 1><<<dim3(W_ / 128, D_ / 128, B_), 512, 0, stream>>>(
        Mbuf, hnormT, nullptr, nullptr, attn, W_, D_, W_,
        (long)W_ * W_, (long)W_ * D_, (long)W_ * D_, 1);

    // 5. h1 = h + attn @ proj_w^T + proj_b   -> d_out (fp32)
    mgemm_kernel<1, 1><<<dim3(B_ * W_ / 128, D_ / 128, 1), 512, 0, stream>>>(
        attn, proj_wb, h, proj_b, h1, B_ * W_, D_, D_, 0, 0, 0, 0);

    // 6. mnorm = rmsnorm(h1, norm2_scale)
    rmsnorm_kernel<<<B_ * W_, 256, 0, stream>>>(h1, norm2_scale, mnorm);

    // 7. t = gelu(mnorm @ up_w^T + up_b)     -> tbuf (bf16)
    mgemm_kernel<2, 1><<<dim3(B_ * W_ / 128, 2 * D_ / 128, 1), 512, 0, stream>>>(
        mnorm, up_wb, nullptr, up_b, tbuf, B_ * W_, 2 * D_, D_, 0, 0, 0, 0);

    // 8. out = h1 + t @ down_w^T + down_b  (h1 aliases d_out, same-idx RMW)
    mgemm_kernel<1, 1><<<dim3(B_ * W_ / 128, D_ / 128, 1), 512, 0, stream>>>(
        tbuf, down_wb, h1, down_b, (float*)d_out, B_ * W_, D_, 2 * D_, 0, 0, 0, 0);
}